// Round 1
// baseline (428.084 us; speedup 1.0000x reference)
//
#include <hip/hip_runtime.h>
#include <math.h>

#define BB 2
#define LL 4096
#define DMODEL 512
#define DINNER 1024
#define DHALF 512
#define DSTATE 16
#define RK 32
#define NCH 64          // x_dbl channels (32 dt + 16 B + 16 C)
#define NC 64           // scan chunks
#define CLEN (LL/NC)    // 64

__device__ __forceinline__ float silu_f(float v) {
    return v / (1.f + __expf(-v));
}

// ---------------- GEMM: out[b][e][l] = sum_k W[e][k] * X[b*L + l][k] ----------------
// W: (E x K) row-major. X rows: (B*L x K) row-major. out: (B, E, L).
template<int E, int K>
__global__ void gemm_we_xl(const float* __restrict__ W, const float* __restrict__ X,
                           float* __restrict__ out) {
    __shared__ __align__(16) float Ws[16][68];
    __shared__ __align__(16) float Xs[16][68];
    const int b = blockIdx.z;
    const int e0 = blockIdx.y * 64;
    const int l0 = blockIdx.x * 64;
    const int tid = threadIdx.x;
    const int tx = tid & 15, ty = tid >> 4;
    const int lr = tid >> 2;          // 0..63
    const int lc = (tid & 3) * 4;     // 0,4,8,12
    float acc[4][4] = {};

    for (int k0 = 0; k0 < K; k0 += 16) {
        float4 wv = *(const float4*)&W[(size_t)(e0 + lr) * K + k0 + lc];
        float4 xv = *(const float4*)&X[((size_t)b * LL + l0 + lr) * K + k0 + lc];
        Ws[lc+0][lr] = wv.x; Ws[lc+1][lr] = wv.y; Ws[lc+2][lr] = wv.z; Ws[lc+3][lr] = wv.w;
        Xs[lc+0][lr] = xv.x; Xs[lc+1][lr] = xv.y; Xs[lc+2][lr] = xv.z; Xs[lc+3][lr] = xv.w;
        __syncthreads();
        #pragma unroll
        for (int kk = 0; kk < 16; ++kk) {
            float4 a = *(const float4*)&Ws[kk][ty * 4];
            float4 bx = *(const float4*)&Xs[kk][tx * 4];
            float av[4] = {a.x, a.y, a.z, a.w};
            float bv[4] = {bx.x, bx.y, bx.z, bx.w};
            #pragma unroll
            for (int i = 0; i < 4; ++i)
                #pragma unroll
                for (int j = 0; j < 4; ++j)
                    acc[i][j] += av[i] * bv[j];
        }
        __syncthreads();
    }
    #pragma unroll
    for (int i = 0; i < 4; ++i) {
        float4 o = make_float4(acc[i][0], acc[i][1], acc[i][2], acc[i][3]);
        *(float4*)&out[((size_t)b * E + e0 + ty * 4 + i) * LL + l0 + tx * 4] = o;
    }
}

// ---------------- conv1d (width 4, SAME: taps l-1..l+2) + silu ----------------
// x-half (c<512): write transposed xq[b][l][c]; z-half: write zb[b][c-512][l].
__global__ void conv_silu(const float* __restrict__ xz,
                          const float* __restrict__ wx, const float* __restrict__ wz,
                          float* __restrict__ xq, float* __restrict__ zb) {
    __shared__ float s[64 * 69];
    const int b = blockIdx.z;
    const int c0 = blockIdx.y * 64;
    const int l0 = blockIdx.x * 64;
    const int tid = threadIdx.x;
    if (c0 < DHALF) {
        for (int idx = tid; idx < 64 * 68; idx += 256) {
            int cc = idx / 68, ll = idx % 68;
            int l = l0 - 1 + ll;
            float v = (l >= 0 && l < LL) ? xz[((size_t)b * DINNER + c0 + cc) * LL + l] : 0.f;
            s[cc * 69 + ll] = v;
        }
        __syncthreads();
        const int cc = tid & 63;
        float4 w = *(const float4*)&wx[(c0 + cc) * 4];
        #pragma unroll
        for (int rep = 0; rep < 16; ++rep) {
            int ll = (tid >> 6) + rep * 4;
            float v = w.x * s[cc*69 + ll] + w.y * s[cc*69 + ll + 1]
                    + w.z * s[cc*69 + ll + 2] + w.w * s[cc*69 + ll + 3];
            xq[((size_t)b * LL + l0 + ll) * DHALF + c0 + cc] = silu_f(v);
        }
    } else {
        const int ll = tid & 63;
        const int l = l0 + ll;
        #pragma unroll
        for (int rep = 0; rep < 16; ++rep) {
            int c = c0 + (tid >> 6) + rep * 4;
            float4 w = *(const float4*)&wz[(c - DHALF) * 4];
            float wv[4] = {w.x, w.y, w.z, w.w};
            float acc = 0.f;
            #pragma unroll
            for (int t = 0; t < 4; ++t) {
                int li = l - 1 + t;
                float v = (li >= 0 && li < LL) ? xz[((size_t)b * DINNER + c) * LL + li] : 0.f;
                acc += wv[t] * v;
            }
            zb[((size_t)b * DHALF + c - DHALF) * LL + l] = silu_f(acc);
        }
    }
}

// ---------------- dt projection + softplus -> delta (b, l, d) ----------------
__global__ void dt_delta(const float* __restrict__ xdbl, const float* __restrict__ dtw,
                         const float* __restrict__ dtb, float* __restrict__ delta) {
    const int b = blockIdx.z;
    const int d = blockIdx.y * 256 + threadIdx.x;
    const int l = blockIdx.x;
    float acc = dtb[d];
    #pragma unroll
    for (int r = 0; r < RK; ++r)
        acc += xdbl[((size_t)b * NCH + r) * LL + l] * dtw[d * RK + r];
    float sp = fmaxf(acc, 0.f) + log1pf(expf(-fabsf(acc)));
    delta[((size_t)b * LL + l) * DHALF + d] = sp;
}

// ---------------- scan pass 1: per-chunk local scan -> (prodA, h_end) ----------------
__global__ void scan1(const float* __restrict__ delta, const float* __restrict__ xq,
                      const float* __restrict__ xdbl, const float* __restrict__ A_log,
                      float* __restrict__ pend, float* __restrict__ hend) {
    const int b = blockIdx.z;
    const int d = blockIdx.y * 256 + threadIdx.x;
    const int c = blockIdx.x;
    float Arow[DSTATE], h[DSTATE], p[DSTATE];
    #pragma unroll
    for (int n = 0; n < DSTATE; ++n) {
        Arow[n] = -expf(A_log[d * DSTATE + n]);
        h[n] = 0.f; p[n] = 1.f;
    }
    const float* Bbase = &xdbl[((size_t)b * NCH + RK) * LL];
    for (int l = c * CLEN; l < (c + 1) * CLEN; ++l) {
        float dl = delta[((size_t)b * LL + l) * DHALF + d];
        float xv = xq[((size_t)b * LL + l) * DHALF + d];
        float dx = dl * xv;
        #pragma unroll
        for (int n = 0; n < DSTATE; ++n) {
            float dA = __expf(dl * Arow[n]);
            h[n] = dA * h[n] + dx * Bbase[(size_t)n * LL + l];
            p[n] *= dA;
        }
    }
    size_t base = (((size_t)b * NC + c) * DSTATE) * DHALF + d;
    #pragma unroll
    for (int n = 0; n < DSTATE; ++n) {
        pend[base + (size_t)n * DHALF] = p[n];
        hend[base + (size_t)n * DHALF] = h[n];
    }
}

// ---------------- scan pass 2: sequential combine across chunks ----------------
__global__ void scan2(const float* __restrict__ pend, const float* __restrict__ hend,
                      float* __restrict__ hin) {
    const int tid = blockIdx.x * 256 + threadIdx.x;  // B*DSTATE*DHALF = 16384
    const int d = tid & (DHALF - 1);
    const int n = (tid >> 9) & (DSTATE - 1);
    const int b = tid >> 13;
    float h = 0.f;
    for (int c = 0; c < NC; ++c) {
        size_t idx = (((size_t)b * NC + c) * DSTATE + n) * DHALF + d;
        hin[idx] = h;
        h = pend[idx] * h + hend[idx];
    }
}

// ---------------- scan pass 3: recompute with carry, emit y (b, l, d) ----------------
__global__ void scan3(const float* __restrict__ delta, const float* __restrict__ xq,
                      const float* __restrict__ xdbl, const float* __restrict__ A_log,
                      const float* __restrict__ Dp, const float* __restrict__ hin,
                      float* __restrict__ ybuf) {
    const int b = blockIdx.z;
    const int d = blockIdx.y * 256 + threadIdx.x;
    const int c = blockIdx.x;
    float Arow[DSTATE], h[DSTATE];
    size_t base = (((size_t)b * NC + c) * DSTATE) * DHALF + d;
    #pragma unroll
    for (int n = 0; n < DSTATE; ++n) {
        Arow[n] = -expf(A_log[d * DSTATE + n]);
        h[n] = hin[base + (size_t)n * DHALF];
    }
    const float Dv = Dp[d];
    const float* Bbase = &xdbl[((size_t)b * NCH + RK) * LL];
    const float* Cbase = &xdbl[((size_t)b * NCH + RK + DSTATE) * LL];
    for (int l = c * CLEN; l < (c + 1) * CLEN; ++l) {
        float dl = delta[((size_t)b * LL + l) * DHALF + d];
        float xv = xq[((size_t)b * LL + l) * DHALF + d];
        float dx = dl * xv;
        float y = Dv * xv;
        #pragma unroll
        for (int n = 0; n < DSTATE; ++n) {
            float dA = __expf(dl * Arow[n]);
            h[n] = dA * h[n] + dx * Bbase[(size_t)n * LL + l];
            y += h[n] * Cbase[(size_t)n * LL + l];
        }
        ybuf[((size_t)b * LL + l) * DHALF + d] = y;
    }
}

// ---------------- out_proj: out[b][l][e] = sum_k Wo[e][k] * ycat[b][k][l] ----------------
// k<512 from ybuf (b,l,d); k>=512 from zb (b,d,l).
__global__ void gemm_out(const float* __restrict__ Wo, const float* __restrict__ ybuf,
                         const float* __restrict__ zb, float* __restrict__ out) {
    __shared__ __align__(16) float As[16][68];
    __shared__ __align__(16) float Bs[16][68];
    const int b = blockIdx.z;
    const int l0 = blockIdx.x * 64;
    const int e0 = blockIdx.y * 64;
    const int tid = threadIdx.x;
    const int tx = tid & 15, ty = tid >> 4;
    const int lr = tid >> 2;
    const int lc = (tid & 3) * 4;
    const int zkk = tid >> 4;            // 0..15
    const int zll = (tid & 15) * 4;      // 0..60
    float acc[4][4] = {};

    for (int k0 = 0; k0 < DINNER; k0 += 16) {
        float4 wv = *(const float4*)&Wo[(size_t)(e0 + lr) * DINNER + k0 + lc];
        Bs[lc+0][lr] = wv.x; Bs[lc+1][lr] = wv.y; Bs[lc+2][lr] = wv.z; Bs[lc+3][lr] = wv.w;
        if (k0 < DHALF) {
            float4 yv = *(const float4*)&ybuf[((size_t)b * LL + l0 + lr) * DHALF + k0 + lc];
            As[lc+0][lr] = yv.x; As[lc+1][lr] = yv.y; As[lc+2][lr] = yv.z; As[lc+3][lr] = yv.w;
        } else {
            float4 zv = *(const float4*)&zb[((size_t)b * DHALF + k0 - DHALF + zkk) * LL + l0 + zll];
            *(float4*)&As[zkk][zll] = zv;
        }
        __syncthreads();
        #pragma unroll
        for (int kk = 0; kk < 16; ++kk) {
            float4 a = *(const float4*)&As[kk][ty * 4];
            float4 bx = *(const float4*)&Bs[kk][tx * 4];
            float av[4] = {a.x, a.y, a.z, a.w};
            float bv[4] = {bx.x, bx.y, bx.z, bx.w};
            #pragma unroll
            for (int i = 0; i < 4; ++i)
                #pragma unroll
                for (int j = 0; j < 4; ++j)
                    acc[i][j] += av[i] * bv[j];
        }
        __syncthreads();
    }
    #pragma unroll
    for (int i = 0; i < 4; ++i) {
        float4 o = make_float4(acc[i][0], acc[i][1], acc[i][2], acc[i][3]);
        *(float4*)&out[((size_t)b * LL + l0 + ty * 4 + i) * DMODEL + e0 + tx * 4] = o;
    }
}

extern "C" void kernel_launch(void* const* d_in, const int* in_sizes, int n_in,
                              void* d_out, int out_size, void* d_ws, size_t ws_size,
                              hipStream_t stream) {
    const float* hidden     = (const float*)d_in[0];
    const float* in_proj_w  = (const float*)d_in[1];
    const float* conv_x_w   = (const float*)d_in[2];
    const float* conv_z_w   = (const float*)d_in[3];
    const float* x_proj_w   = (const float*)d_in[4];
    const float* dt_proj_w  = (const float*)d_in[5];
    const float* dt_proj_b  = (const float*)d_in[6];
    const float* A_log      = (const float*)d_in[7];
    const float* Dp         = (const float*)d_in[8];
    const float* out_proj_w = (const float*)d_in[9];
    float* out = (float*)d_out;

    float* ws = (float*)d_ws;
    float* xz   = ws;                                   // B*DINNER*LL = 8M floats
    float* xq   = xz + (size_t)BB * DINNER * LL;        // B*LL*DHALF = 4M
    float* zb   = xq + (size_t)BB * LL * DHALF;         // 4M
    float* xdbl = zb + (size_t)BB * DHALF * LL;         // B*NCH*LL = 0.5M
    float* pend = xdbl + (size_t)BB * NCH * LL;         // B*NC*DSTATE*DHALF = 1M
    float* hend = pend + (size_t)BB * NC * DSTATE * DHALF;
    float* hin  = hend + (size_t)BB * NC * DSTATE * DHALF;
    // alias dead xz region after conv: delta + ybuf
    float* delta = xz;                                  // 4M (xz dead after conv)
    float* ybuf  = xz + (size_t)BB * LL * DHALF;        // 4M

    dim3 blk(256);

    // K1: in_proj -> xz (b, 1024, l)
    gemm_we_xl<DINNER, DMODEL><<<dim3(LL/64, DINNER/64, BB), blk, 0, stream>>>(in_proj_w, hidden, xz);
    // K2: conv + silu -> xq (b,l,d), zb (b,d,l)
    conv_silu<<<dim3(LL/64, DINNER/64, BB), blk, 0, stream>>>(xz, conv_x_w, conv_z_w, xq, zb);
    // K3: x_proj -> xdbl (b, 64, l)
    gemm_we_xl<NCH, DHALF><<<dim3(LL/64, 1, BB), blk, 0, stream>>>(x_proj_w, xq, xdbl);
    // K4: dt proj + softplus -> delta (b,l,d)   [xz region now dead -> reuse]
    dt_delta<<<dim3(LL, DHALF/256, BB), blk, 0, stream>>>(xdbl, dt_proj_w, dt_proj_b, delta);
    // K5: chunk-local scan
    scan1<<<dim3(NC, DHALF/256, BB), blk, 0, stream>>>(delta, xq, xdbl, A_log, pend, hend);
    // K5b: cross-chunk combine
    scan2<<<dim3(BB * DSTATE * DHALF / 256), blk, 0, stream>>>(pend, hend, hin);
    // K6: recompute with carry, emit y (b,l,d)
    scan3<<<dim3(NC, DHALF/256, BB), blk, 0, stream>>>(delta, xq, xdbl, A_log, Dp, hin, ybuf);
    // K7: out_proj -> out (b,l,e)
    gemm_out<<<dim3(LL/64, DMODEL/64, BB), blk, 0, stream>>>(out_proj_w, ybuf, zb, out);
}

// Round 2
// 240.095 us; speedup vs baseline: 1.7830x; 1.7830x over previous
//
#include <hip/hip_runtime.h>
#include <math.h>

#define BB 2
#define LL 4096
#define DMODEL 512
#define DINNER 1024
#define DHALF 512
#define DSTATE 16
#define RK 32
#define NCH 64          // x_dbl channels (32 dt + 16 B + 16 C)
#define NC 64           // scan chunks
#define CLEN (LL/NC)    // 64

typedef __attribute__((ext_vector_type(8))) short short8;
typedef __attribute__((ext_vector_type(4))) float f32x4;

__device__ __forceinline__ float silu_f(float v) { return v / (1.f + __expf(-v)); }

// round-to-nearest-even fp32 -> bf16 (inputs finite)
__device__ __forceinline__ unsigned short f2bf(float x) {
    unsigned int u = __float_as_uint(x);
    u += 0x7fffu + ((u >> 16) & 1u);
    return (unsigned short)(u >> 16);
}

__device__ __forceinline__ void gload16(const unsigned short* g, unsigned short* l) {
    __builtin_amdgcn_global_load_lds((const __attribute__((address_space(1))) void*)g,
                                     (__attribute__((address_space(3))) void*)l, 16, 0, 0);
}

// ---------------- cast fp32 -> bf16, 4 elems/thread ----------------
__global__ void cast_bf16_k(const float* __restrict__ src, unsigned short* __restrict__ dst, int n4) {
    int i = blockIdx.x * 256 + threadIdx.x;
    if (i >= n4) return;
    float4 v = *(const float4*)&src[(size_t)i * 4];
    ushort4 o = make_ushort4(f2bf(v.x), f2bf(v.y), f2bf(v.z), f2bf(v.w));
    *(ushort4*)&dst[(size_t)i * 4] = o;
}

// ---------------- bf16 MFMA GEMM ----------------
// W: [E][K] bf16 k-major.  X: [R][K] bf16 k-major (R = B*LL rows).
// out: [R][E] fp32.   out[r][e] = sum_k W[e][k] * X[r][k]
// 128x128 tile, BK=64, 4 waves (2x2), each wave 64e x 64l = 4x4 16x16 frags.
template<int K, int E>
__global__ __launch_bounds__(256) void gemm_mfma(const unsigned short* __restrict__ W,
                                                 const unsigned short* __restrict__ X,
                                                 float* __restrict__ out) {
    __shared__ unsigned short Wa[128 * 64];   // [row][k], 16B-chunk XOR-swizzled
    __shared__ unsigned short Xa[128 * 64];
    const int tid = threadIdx.x;
    const int lane = tid & 63;
    const int w = tid >> 6;
    const int wr = w >> 1, wc = w & 1;
    const int frow = lane & 15;
    const int kg = lane >> 4;                 // 0..3
    const int e0 = blockIdx.y * 128;
    const int r0 = blockIdx.x * 128;

    f32x4 acc[4][4] = {};

    for (int kt = 0; kt < K / 64; ++kt) {
        // stage: linear LDS dest, inverse-swizzled global source (rule #21)
        #pragma unroll
        for (int i = 0; i < 4; ++i) {
            int flat = i * 256 + tid;         // 0..1023, 16B units
            int row = flat >> 3;
            int slot = flat & 7;
            int chunk = slot ^ (row & 7);
            gload16(&W[(size_t)(e0 + row) * K + kt * 64 + chunk * 8], &Wa[flat * 8]);
            gload16(&X[(size_t)(r0 + row) * K + kt * 64 + chunk * 8], &Xa[flat * 8]);
        }
        __syncthreads();   // drains vmcnt (global_load_lds) + lgkm

        #pragma unroll
        for (int ks = 0; ks < 2; ++ks) {
            short8 af[4], bfr[4];
            #pragma unroll
            for (int m = 0; m < 4; ++m) {
                int row = wr * 64 + m * 16 + frow;
                int phys = (ks * 4 + kg) ^ (row & 7);
                af[m] = *(const short8*)&Wa[row * 64 + phys * 8];
            }
            #pragma unroll
            for (int n = 0; n < 4; ++n) {
                int row = wc * 64 + n * 16 + frow;
                int phys = (ks * 4 + kg) ^ (row & 7);
                bfr[n] = *(const short8*)&Xa[row * 64 + phys * 8];
            }
            #pragma unroll
            for (int m = 0; m < 4; ++m)
                #pragma unroll
                for (int n = 0; n < 4; ++n)
                    acc[m][n] = __builtin_amdgcn_mfma_f32_16x16x32_bf16(af[m], bfr[n], acc[m][n], 0, 0, 0);
        }
        __syncthreads();
    }

    // C/D: col(l) = lane&15, row(e) = (lane>>4)*4 + reg  -> float4 store along e
    #pragma unroll
    for (int m = 0; m < 4; ++m) {
        #pragma unroll
        for (int n = 0; n < 4; ++n) {
            int e = e0 + wr * 64 + m * 16 + kg * 4;
            int r = r0 + wc * 64 + n * 16 + frow;
            *(f32x4*)&out[(size_t)r * E + e] = acc[m][n];
        }
    }
}

// ---------------- conv1d (width 4, taps l-1..l+2) + silu ----------------
// xz: (b, l, 1024).  x-half (c<512) -> xq fp32 (b,l,512); z-half -> ycb bf16 (b,l,1024) cols 512..1023
__global__ void conv_silu(const float* __restrict__ xz,
                          const float* __restrict__ wx, const float* __restrict__ wz,
                          float* __restrict__ xq, unsigned short* __restrict__ ycb) {
    __shared__ float s[67][64];
    const int b = blockIdx.z;
    const int l0 = blockIdx.x * 64;
    const int c0 = blockIdx.y * 64;
    const int tid = threadIdx.x;
    for (int idx = tid; idx < 67 * 64; idx += 256) {
        int rr = idx >> 6, cc = idx & 63;
        int l = l0 - 1 + rr;
        s[rr][cc] = (l >= 0 && l < LL) ? xz[((size_t)b * LL + l) * DINNER + c0 + cc] : 0.f;
    }
    __syncthreads();
    const int cc = tid & 63;
    const int c = c0 + cc;
    const bool isx = (c < DHALF);
    const float* wp = isx ? &wx[c * 4] : &wz[(c - DHALF) * 4];
    float4 w = *(const float4*)wp;
    #pragma unroll
    for (int rep = 0; rep < 16; ++rep) {
        int ll = (tid >> 6) + rep * 4;
        float v = w.x * s[ll][cc] + w.y * s[ll + 1][cc] + w.z * s[ll + 2][cc] + w.w * s[ll + 3][cc];
        v = silu_f(v);
        int l = l0 + ll;
        if (isx) xq[((size_t)b * LL + l) * DHALF + c] = v;
        else     ycb[((size_t)b * LL + l) * DINNER + c] = f2bf(v);
    }
}

// ---------------- fp32 tiled GEMM (kept for skinny x_proj) ----------------
// out[b][e][l] = sum_k W[e][k] * X[b*L + l][k]
template<int E, int K>
__global__ void gemm_we_xl(const float* __restrict__ W, const float* __restrict__ X,
                           float* __restrict__ out) {
    __shared__ __align__(16) float Ws[16][68];
    __shared__ __align__(16) float Xs[16][68];
    const int b = blockIdx.z;
    const int e0 = blockIdx.y * 64;
    const int l0 = blockIdx.x * 64;
    const int tid = threadIdx.x;
    const int tx = tid & 15, ty = tid >> 4;
    const int lr = tid >> 2;
    const int lc = (tid & 3) * 4;
    float acc[4][4] = {};

    for (int k0 = 0; k0 < K; k0 += 16) {
        float4 wv = *(const float4*)&W[(size_t)(e0 + lr) * K + k0 + lc];
        float4 xv = *(const float4*)&X[((size_t)b * LL + l0 + lr) * K + k0 + lc];
        Ws[lc+0][lr] = wv.x; Ws[lc+1][lr] = wv.y; Ws[lc+2][lr] = wv.z; Ws[lc+3][lr] = wv.w;
        Xs[lc+0][lr] = xv.x; Xs[lc+1][lr] = xv.y; Xs[lc+2][lr] = xv.z; Xs[lc+3][lr] = xv.w;
        __syncthreads();
        #pragma unroll
        for (int kk = 0; kk < 16; ++kk) {
            float4 a = *(const float4*)&Ws[kk][ty * 4];
            float4 bx = *(const float4*)&Xs[kk][tx * 4];
            float av[4] = {a.x, a.y, a.z, a.w};
            float bv[4] = {bx.x, bx.y, bx.z, bx.w};
            #pragma unroll
            for (int i = 0; i < 4; ++i)
                #pragma unroll
                for (int j = 0; j < 4; ++j)
                    acc[i][j] += av[i] * bv[j];
        }
        __syncthreads();
    }
    #pragma unroll
    for (int i = 0; i < 4; ++i) {
        float4 o = make_float4(acc[i][0], acc[i][1], acc[i][2], acc[i][3]);
        *(float4*)&out[((size_t)b * E + e0 + ty * 4 + i) * LL + l0 + tx * 4] = o;
    }
}

// ---------------- dt projection + softplus -> delta (b, l, d) ----------------
__global__ void dt_delta(const float* __restrict__ xdbl, const float* __restrict__ dtw,
                         const float* __restrict__ dtb, float* __restrict__ delta) {
    const int b = blockIdx.z;
    const int d = blockIdx.y * 256 + threadIdx.x;
    const int l = blockIdx.x;
    float acc = dtb[d];
    #pragma unroll
    for (int r = 0; r < RK; ++r)
        acc += xdbl[((size_t)b * NCH + r) * LL + l] * dtw[d * RK + r];
    float sp = fmaxf(acc, 0.f) + log1pf(expf(-fabsf(acc)));
    delta[((size_t)b * LL + l) * DHALF + d] = sp;
}

// ---------------- scan pass 1: per-chunk local scan -> (prodA, h_end) ----------------
__global__ void scan1(const float* __restrict__ delta, const float* __restrict__ xq,
                      const float* __restrict__ xdbl, const float* __restrict__ A_log,
                      float* __restrict__ pend, float* __restrict__ hend) {
    const int b = blockIdx.z;
    const int d = blockIdx.y * 256 + threadIdx.x;
    const int c = blockIdx.x;
    float Arow[DSTATE], h[DSTATE], p[DSTATE];
    #pragma unroll
    for (int n = 0; n < DSTATE; ++n) {
        Arow[n] = -expf(A_log[d * DSTATE + n]);
        h[n] = 0.f; p[n] = 1.f;
    }
    const float* Bbase = &xdbl[((size_t)b * NCH + RK) * LL];
    for (int l = c * CLEN; l < (c + 1) * CLEN; ++l) {
        float dl = delta[((size_t)b * LL + l) * DHALF + d];
        float xv = xq[((size_t)b * LL + l) * DHALF + d];
        float dx = dl * xv;
        #pragma unroll
        for (int n = 0; n < DSTATE; ++n) {
            float dA = __expf(dl * Arow[n]);
            h[n] = dA * h[n] + dx * Bbase[(size_t)n * LL + l];
            p[n] *= dA;
        }
    }
    size_t base = (((size_t)b * NC + c) * DSTATE) * DHALF + d;
    #pragma unroll
    for (int n = 0; n < DSTATE; ++n) {
        pend[base + (size_t)n * DHALF] = p[n];
        hend[base + (size_t)n * DHALF] = h[n];
    }
}

// ---------------- scan pass 2: sequential combine across chunks ----------------
__global__ void scan2(const float* __restrict__ pend, const float* __restrict__ hend,
                      float* __restrict__ hin) {
    const int tid = blockIdx.x * 256 + threadIdx.x;  // B*DSTATE*DHALF = 16384
    const int d = tid & (DHALF - 1);
    const int n = (tid >> 9) & (DSTATE - 1);
    const int b = tid >> 13;
    float h = 0.f;
    for (int c = 0; c < NC; ++c) {
        size_t idx = (((size_t)b * NC + c) * DSTATE + n) * DHALF + d;
        hin[idx] = h;
        h = pend[idx] * h + hend[idx];
    }
}

// ---------------- scan pass 3: recompute with carry, emit y -> ycb bf16 cols 0..511 ----------------
__global__ void scan3(const float* __restrict__ delta, const float* __restrict__ xq,
                      const float* __restrict__ xdbl, const float* __restrict__ A_log,
                      const float* __restrict__ Dp, const float* __restrict__ hin,
                      unsigned short* __restrict__ ycb) {
    const int b = blockIdx.z;
    const int d = blockIdx.y * 256 + threadIdx.x;
    const int c = blockIdx.x;
    float Arow[DSTATE], h[DSTATE];
    size_t base = (((size_t)b * NC + c) * DSTATE) * DHALF + d;
    #pragma unroll
    for (int n = 0; n < DSTATE; ++n) {
        Arow[n] = -expf(A_log[d * DSTATE + n]);
        h[n] = hin[base + (size_t)n * DHALF];
    }
    const float Dv = Dp[d];
    const float* Bbase = &xdbl[((size_t)b * NCH + RK) * LL];
    const float* Cbase = &xdbl[((size_t)b * NCH + RK + DSTATE) * LL];
    for (int l = c * CLEN; l < (c + 1) * CLEN; ++l) {
        float dl = delta[((size_t)b * LL + l) * DHALF + d];
        float xv = xq[((size_t)b * LL + l) * DHALF + d];
        float dx = dl * xv;
        float y = Dv * xv;
        #pragma unroll
        for (int n = 0; n < DSTATE; ++n) {
            float dA = __expf(dl * Arow[n]);
            h[n] = dA * h[n] + dx * Bbase[(size_t)n * LL + l];
            y += h[n] * Cbase[(size_t)n * LL + l];
        }
        ycb[((size_t)b * LL + l) * DINNER + d] = f2bf(y);
    }
}

extern "C" void kernel_launch(void* const* d_in, const int* in_sizes, int n_in,
                              void* d_out, int out_size, void* d_ws, size_t ws_size,
                              hipStream_t stream) {
    const float* hidden     = (const float*)d_in[0];
    const float* in_proj_w  = (const float*)d_in[1];
    const float* conv_x_w   = (const float*)d_in[2];
    const float* conv_z_w   = (const float*)d_in[3];
    const float* x_proj_w   = (const float*)d_in[4];
    const float* dt_proj_w  = (const float*)d_in[5];
    const float* dt_proj_b  = (const float*)d_in[6];
    const float* A_log      = (const float*)d_in[7];
    const float* Dp         = (const float*)d_in[8];
    const float* out_proj_w = (const float*)d_in[9];
    float* out = (float*)d_out;

    const size_t M = 1024 * 1024;
    float* ws_f = (float*)d_ws;
    float* xz   = ws_f;                          // 8M floats (b,l,1024)   [K1 -> K2]
    float* xq   = ws_f + 8 * M;                  // 4M (b,l,512)           [K2 -> K6]
    float* xdbl = ws_f + 12 * M;                 // 0.5M (b,64,l)          [K3 -> K6]
    unsigned short* ycb = (unsigned short*)(ws_f + 12 * M + 512 * 1024);  // 8M bf16 (b,l,1024)
    unsigned short* Hb  = (unsigned short*)(ws_f + 16 * M + 512 * 1024);  // 4M bf16
    unsigned short* Wb  = (unsigned short*)(ws_f + 18 * M + 512 * 1024);  // 0.5M bf16
    unsigned short* Wob = (unsigned short*)(ws_f + 18 * M + 768 * 1024);  // 0.5M bf16
    // aliases onto xz (dead after conv):
    float* delta = xz;                           // 4M (b,l,512)
    float* pend  = xz + 4 * M;                   // 1M
    float* hend  = xz + 5 * M;                   // 1M
    float* hin   = xz + 6 * M;                   // 1M

    dim3 blk(256);

    // casts to bf16
    cast_bf16_k<<<dim3((BB * LL * DMODEL / 4 + 255) / 256), blk, 0, stream>>>(hidden, Hb, BB * LL * DMODEL / 4);
    cast_bf16_k<<<dim3((DINNER * DMODEL / 4 + 255) / 256), blk, 0, stream>>>(in_proj_w, Wb, DINNER * DMODEL / 4);
    cast_bf16_k<<<dim3((DMODEL * DINNER / 4 + 255) / 256), blk, 0, stream>>>(out_proj_w, Wob, DMODEL * DINNER / 4);

    // K1: in_proj (bf16 MFMA) -> xz (b,l,1024) fp32
    gemm_mfma<DMODEL, DINNER><<<dim3(BB * LL / 128, DINNER / 128), blk, 0, stream>>>(Wb, Hb, xz);
    // K2: conv + silu -> xq fp32 (b,l,512); z-half -> ycb bf16 cols 512..1023
    conv_silu<<<dim3(LL / 64, DINNER / 64, BB), blk, 0, stream>>>(xz, conv_x_w, conv_z_w, xq, ycb);
    // K3: x_proj (fp32) -> xdbl (b,64,l)
    gemm_we_xl<NCH, DHALF><<<dim3(LL / 64, 1, BB), blk, 0, stream>>>(x_proj_w, xq, xdbl);
    // K4: dt proj + softplus -> delta (b,l,512)  [xz dead -> aliased]
    dt_delta<<<dim3(LL, DHALF / 256, BB), blk, 0, stream>>>(xdbl, dt_proj_w, dt_proj_b, delta);
    // K5: chunk-local scan
    scan1<<<dim3(NC, DHALF / 256, BB), blk, 0, stream>>>(delta, xq, xdbl, A_log, pend, hend);
    // K5b: cross-chunk combine
    scan2<<<dim3(BB * DSTATE * DHALF / 256), blk, 0, stream>>>(pend, hend, hin);
    // K6: recompute with carry -> ycb bf16 cols 0..511
    scan3<<<dim3(NC, DHALF / 256, BB), blk, 0, stream>>>(delta, xq, xdbl, A_log, Dp, hin, ycb);
    // K7: out_proj (bf16 MFMA) -> out (b,l,512) fp32
    gemm_mfma<DINNER, DMODEL><<<dim3(BB * LL / 128, DMODEL / 128), blk, 0, stream>>>(Wob, ycb, out);
}

// Round 3
// 174.101 us; speedup vs baseline: 2.4588x; 1.3791x over previous
//
#include <hip/hip_runtime.h>
#include <math.h>

#define BB 2
#define LL 4096
#define DMODEL 512
#define DINNER 1024
#define DHALF 512
#define DSTATE 16
#define RK 32
#define NCH 64          // x_dbl channels (32 dt + 16 B + 16 C)
#define NC 256          // scan chunks
#define CLEN (LL/NC)    // 16

typedef __attribute__((ext_vector_type(8))) short short8;
typedef __attribute__((ext_vector_type(4))) float f32x4;

__device__ __forceinline__ float silu_f(float v) { return v / (1.f + __expf(-v)); }

// round-to-nearest-even fp32 -> bf16 (inputs finite)
__device__ __forceinline__ unsigned short f2bf(float x) {
    unsigned int u = __float_as_uint(x);
    u += 0x7fffu + ((u >> 16) & 1u);
    return (unsigned short)(u >> 16);
}

__device__ __forceinline__ float softplus_f(float x) {
    return fmaxf(x, 0.f) + __logf(1.f + __expf(-fabsf(x)));
}

__device__ __forceinline__ void gload16(const unsigned short* g, unsigned short* l) {
    __builtin_amdgcn_global_load_lds((const __attribute__((address_space(1))) void*)g,
                                     (__attribute__((address_space(3))) void*)l, 16, 0, 0);
}

// ---------------- cast fp32 -> bf16, 4 elems/thread ----------------
__global__ void cast_bf16_k(const float* __restrict__ src, unsigned short* __restrict__ dst, int n4) {
    int i = blockIdx.x * 256 + threadIdx.x;
    if (i >= n4) return;
    float4 v = *(const float4*)&src[(size_t)i * 4];
    ushort4 o = make_ushort4(f2bf(v.x), f2bf(v.y), f2bf(v.z), f2bf(v.w));
    *(ushort4*)&dst[(size_t)i * 4] = o;
}

// ---------------- bf16 MFMA GEMM ----------------
// W: [E][K] bf16 k-major.  X: [R][K] bf16 k-major (R = B*LL rows).
// out: [R][E] fp32.   out[r][e] = sum_k W[e][k] * X[r][k]
template<int K, int E>
__global__ __launch_bounds__(256) void gemm_mfma(const unsigned short* __restrict__ W,
                                                 const unsigned short* __restrict__ X,
                                                 float* __restrict__ out) {
    __shared__ unsigned short Wa[128 * 64];   // [row][k], 16B-chunk XOR-swizzled
    __shared__ unsigned short Xa[128 * 64];
    const int tid = threadIdx.x;
    const int lane = tid & 63;
    const int w = tid >> 6;
    const int wr = w >> 1, wc = w & 1;
    const int frow = lane & 15;
    const int kg = lane >> 4;                 // 0..3
    const int e0 = blockIdx.y * 128;
    const int r0 = blockIdx.x * 128;

    f32x4 acc[4][4] = {};

    for (int kt = 0; kt < K / 64; ++kt) {
        #pragma unroll
        for (int i = 0; i < 4; ++i) {
            int flat = i * 256 + tid;         // 0..1023, 16B units
            int row = flat >> 3;
            int slot = flat & 7;
            int chunk = slot ^ (row & 7);
            gload16(&W[(size_t)(e0 + row) * K + kt * 64 + chunk * 8], &Wa[flat * 8]);
            gload16(&X[(size_t)(r0 + row) * K + kt * 64 + chunk * 8], &Xa[flat * 8]);
        }
        __syncthreads();

        #pragma unroll
        for (int ks = 0; ks < 2; ++ks) {
            short8 af[4], bfr[4];
            #pragma unroll
            for (int m = 0; m < 4; ++m) {
                int row = wr * 64 + m * 16 + frow;
                int phys = (ks * 4 + kg) ^ (row & 7);
                af[m] = *(const short8*)&Wa[row * 64 + phys * 8];
            }
            #pragma unroll
            for (int n = 0; n < 4; ++n) {
                int row = wc * 64 + n * 16 + frow;
                int phys = (ks * 4 + kg) ^ (row & 7);
                bfr[n] = *(const short8*)&Xa[row * 64 + phys * 8];
            }
            #pragma unroll
            for (int m = 0; m < 4; ++m)
                #pragma unroll
                for (int n = 0; n < 4; ++n)
                    acc[m][n] = __builtin_amdgcn_mfma_f32_16x16x32_bf16(af[m], bfr[n], acc[m][n], 0, 0, 0);
        }
        __syncthreads();
    }

    #pragma unroll
    for (int m = 0; m < 4; ++m) {
        #pragma unroll
        for (int n = 0; n < 4; ++n) {
            int e = e0 + wr * 64 + m * 16 + kg * 4;
            int r = r0 + wc * 64 + n * 16 + frow;
            *(f32x4*)&out[(size_t)r * E + e] = acc[m][n];
        }
    }
}

// ---------------- conv1d (width 4, taps l-1..l+2) + silu ----------------
__global__ void conv_silu(const float* __restrict__ xz,
                          const float* __restrict__ wx, const float* __restrict__ wz,
                          float* __restrict__ xq, unsigned short* __restrict__ ycb) {
    __shared__ float s[67][64];
    const int b = blockIdx.z;
    const int l0 = blockIdx.x * 64;
    const int c0 = blockIdx.y * 64;
    const int tid = threadIdx.x;
    for (int idx = tid; idx < 67 * 64; idx += 256) {
        int rr = idx >> 6, cc = idx & 63;
        int l = l0 - 1 + rr;
        s[rr][cc] = (l >= 0 && l < LL) ? xz[((size_t)b * LL + l) * DINNER + c0 + cc] : 0.f;
    }
    __syncthreads();
    const int cc = tid & 63;
    const int c = c0 + cc;
    const bool isx = (c < DHALF);
    const float* wp = isx ? &wx[c * 4] : &wz[(c - DHALF) * 4];
    float4 w = *(const float4*)wp;
    #pragma unroll
    for (int rep = 0; rep < 16; ++rep) {
        int ll = (tid >> 6) + rep * 4;
        float v = w.x * s[ll][cc] + w.y * s[ll + 1][cc] + w.z * s[ll + 2][cc] + w.w * s[ll + 3][cc];
        v = silu_f(v);
        int l = l0 + ll;
        if (isx) xq[((size_t)b * LL + l) * DHALF + c] = v;
        else     ycb[((size_t)b * LL + l) * DINNER + c] = f2bf(v);
    }
}

// ---------------- fp32 tiled GEMM (skinny x_proj) ----------------
// out[b][e][l] = sum_k W[e][k] * X[b*L + l][k]
template<int E, int K>
__global__ void gemm_we_xl(const float* __restrict__ W, const float* __restrict__ X,
                           float* __restrict__ out) {
    __shared__ __align__(16) float Ws[16][68];
    __shared__ __align__(16) float Xs[16][68];
    const int b = blockIdx.z;
    const int e0 = blockIdx.y * 64;
    const int l0 = blockIdx.x * 64;
    const int tid = threadIdx.x;
    const int tx = tid & 15, ty = tid >> 4;
    const int lr = tid >> 2;
    const int lc = (tid & 3) * 4;
    float acc[4][4] = {};

    for (int k0 = 0; k0 < K; k0 += 16) {
        float4 wv = *(const float4*)&W[(size_t)(e0 + lr) * K + k0 + lc];
        float4 xv = *(const float4*)&X[((size_t)b * LL + l0 + lr) * K + k0 + lc];
        Ws[lc+0][lr] = wv.x; Ws[lc+1][lr] = wv.y; Ws[lc+2][lr] = wv.z; Ws[lc+3][lr] = wv.w;
        Xs[lc+0][lr] = xv.x; Xs[lc+1][lr] = xv.y; Xs[lc+2][lr] = xv.z; Xs[lc+3][lr] = xv.w;
        __syncthreads();
        #pragma unroll
        for (int kk = 0; kk < 16; ++kk) {
            float4 a = *(const float4*)&Ws[kk][ty * 4];
            float4 bx = *(const float4*)&Xs[kk][tx * 4];
            float av[4] = {a.x, a.y, a.z, a.w};
            float bv[4] = {bx.x, bx.y, bx.z, bx.w};
            #pragma unroll
            for (int i = 0; i < 4; ++i)
                #pragma unroll
                for (int j = 0; j < 4; ++j)
                    acc[i][j] += av[i] * bv[j];
        }
        __syncthreads();
    }
    #pragma unroll
    for (int i = 0; i < 4; ++i) {
        float4 o = make_float4(acc[i][0], acc[i][1], acc[i][2], acc[i][3]);
        *(float4*)&out[((size_t)b * E + e0 + ty * 4 + i) * LL + l0 + tx * 4] = o;
    }
}

// ---------------- scan pass 1: fused dt + chunk-local scan -> (prodA, h_end) ----------------
// xdbl (b, 64, l): ch 0..31 = dt_rank rows, 32..47 = B, 48..63 = C
__global__ __launch_bounds__(256) void scan1(const float* __restrict__ xq,
                      const float* __restrict__ xdbl, const float* __restrict__ A_log,
                      const float* __restrict__ dtw, const float* __restrict__ dtb,
                      float* __restrict__ pend, float* __restrict__ hend) {
    __shared__ float s[48][CLEN];       // dt rows + B rows
    const int b = blockIdx.z;
    const int d = blockIdx.y * 256 + threadIdx.x;
    const int c = blockIdx.x;
    const int tid = threadIdx.x;
    for (int idx = tid; idx < 48 * CLEN; idx += 256) {
        int ch = idx >> 4, ll = idx & (CLEN - 1);
        s[ch][ll] = xdbl[((size_t)b * NCH + ch) * LL + c * CLEN + ll];
    }
    float dtwreg[RK];
    #pragma unroll
    for (int r = 0; r < RK; r += 4) {
        float4 v = *(const float4*)&dtw[d * RK + r];
        dtwreg[r] = v.x; dtwreg[r+1] = v.y; dtwreg[r+2] = v.z; dtwreg[r+3] = v.w;
    }
    float Arow[DSTATE];
    #pragma unroll
    for (int n = 0; n < DSTATE; ++n) Arow[n] = -expf(A_log[d * DSTATE + n]);
    const float bias = dtb[d];
    float del[CLEN];
    #pragma unroll
    for (int t = 0; t < CLEN; ++t) del[t] = bias;
    __syncthreads();
    #pragma unroll
    for (int r = 0; r < RK; ++r) {
        float wv = dtwreg[r];
        #pragma unroll
        for (int q = 0; q < CLEN / 4; ++q) {
            float4 v = *(const float4*)&s[r][q * 4];
            del[q*4+0] = fmaf(v.x, wv, del[q*4+0]);
            del[q*4+1] = fmaf(v.y, wv, del[q*4+1]);
            del[q*4+2] = fmaf(v.z, wv, del[q*4+2]);
            del[q*4+3] = fmaf(v.w, wv, del[q*4+3]);
        }
    }
    #pragma unroll
    for (int t = 0; t < CLEN; ++t) del[t] = softplus_f(del[t]);

    float h[DSTATE], p[DSTATE];
    #pragma unroll
    for (int n = 0; n < DSTATE; ++n) { h[n] = 0.f; p[n] = 1.f; }
    #pragma unroll
    for (int t = 0; t < CLEN; ++t) {
        float dl = del[t];
        float xv = xq[((size_t)b * LL + c * CLEN + t) * DHALF + d];
        float dx = dl * xv;
        #pragma unroll
        for (int n = 0; n < DSTATE; ++n) {
            float dA = __expf(dl * Arow[n]);
            h[n] = fmaf(dA, h[n], dx * s[32 + n][t]);
            p[n] *= dA;
        }
    }
    size_t base = (((size_t)b * NC + c) * DSTATE) * DHALF + d;
    #pragma unroll
    for (int n = 0; n < DSTATE; ++n) {
        pend[base + (size_t)n * DHALF] = p[n];
        hend[base + (size_t)n * DHALF] = h[n];
    }
}

// ---------------- scan pass 2: sequential combine; hend becomes carry-IN (in place) ----------------
__global__ void scan2(const float* __restrict__ pend, float* __restrict__ hend) {
    const int tid = blockIdx.x * 256 + threadIdx.x;  // B*DSTATE*DHALF = 16384
    const int d = tid & (DHALF - 1);
    const int n = (tid >> 9) & (DSTATE - 1);
    const int b = tid >> 13;
    float h = 0.f;
    size_t idx = (((size_t)b * NC) * DSTATE + n) * DHALF + d;
    for (int c = 0; c < NC; ++c) {
        float pv = pend[idx];
        float ev = hend[idx];
        hend[idx] = h;            // store carry-in for chunk c
        h = fmaf(pv, h, ev);
        idx += (size_t)DSTATE * DHALF;
    }
}

// ---------------- scan pass 3: fused dt + recompute with carry -> ycb bf16 cols 0..511 ----------------
__global__ __launch_bounds__(256) void scan3(const float* __restrict__ xq,
                      const float* __restrict__ xdbl, const float* __restrict__ A_log,
                      const float* __restrict__ dtw, const float* __restrict__ dtb,
                      const float* __restrict__ Dp, const float* __restrict__ hin,
                      unsigned short* __restrict__ ycb) {
    __shared__ float s[64][CLEN];       // dt rows + B rows + C rows
    const int b = blockIdx.z;
    const int d = blockIdx.y * 256 + threadIdx.x;
    const int c = blockIdx.x;
    const int tid = threadIdx.x;
    for (int idx = tid; idx < 64 * CLEN; idx += 256) {
        int ch = idx >> 4, ll = idx & (CLEN - 1);
        s[ch][ll] = xdbl[((size_t)b * NCH + ch) * LL + c * CLEN + ll];
    }
    float dtwreg[RK];
    #pragma unroll
    for (int r = 0; r < RK; r += 4) {
        float4 v = *(const float4*)&dtw[d * RK + r];
        dtwreg[r] = v.x; dtwreg[r+1] = v.y; dtwreg[r+2] = v.z; dtwreg[r+3] = v.w;
    }
    float Arow[DSTATE], h[DSTATE];
    size_t base = (((size_t)b * NC + c) * DSTATE) * DHALF + d;
    #pragma unroll
    for (int n = 0; n < DSTATE; ++n) {
        Arow[n] = -expf(A_log[d * DSTATE + n]);
        h[n] = hin[base + (size_t)n * DHALF];
    }
    const float bias = dtb[d];
    const float Dv = Dp[d];
    float del[CLEN];
    #pragma unroll
    for (int t = 0; t < CLEN; ++t) del[t] = bias;
    __syncthreads();
    #pragma unroll
    for (int r = 0; r < RK; ++r) {
        float wv = dtwreg[r];
        #pragma unroll
        for (int q = 0; q < CLEN / 4; ++q) {
            float4 v = *(const float4*)&s[r][q * 4];
            del[q*4+0] = fmaf(v.x, wv, del[q*4+0]);
            del[q*4+1] = fmaf(v.y, wv, del[q*4+1]);
            del[q*4+2] = fmaf(v.z, wv, del[q*4+2]);
            del[q*4+3] = fmaf(v.w, wv, del[q*4+3]);
        }
    }
    #pragma unroll
    for (int t = 0; t < CLEN; ++t) del[t] = softplus_f(del[t]);

    #pragma unroll
    for (int t = 0; t < CLEN; ++t) {
        float dl = del[t];
        float xv = xq[((size_t)b * LL + c * CLEN + t) * DHALF + d];
        float dx = dl * xv;
        float y = Dv * xv;
        #pragma unroll
        for (int n = 0; n < DSTATE; ++n) {
            float dA = __expf(dl * Arow[n]);
            h[n] = fmaf(dA, h[n], dx * s[32 + n][t]);
            y = fmaf(h[n], s[48 + n][t], y);
        }
        ycb[((size_t)b * LL + c * CLEN + t) * DINNER + d] = f2bf(y);
    }
}

extern "C" void kernel_launch(void* const* d_in, const int* in_sizes, int n_in,
                              void* d_out, int out_size, void* d_ws, size_t ws_size,
                              hipStream_t stream) {
    const float* hidden     = (const float*)d_in[0];
    const float* in_proj_w  = (const float*)d_in[1];
    const float* conv_x_w   = (const float*)d_in[2];
    const float* conv_z_w   = (const float*)d_in[3];
    const float* x_proj_w   = (const float*)d_in[4];
    const float* dt_proj_w  = (const float*)d_in[5];
    const float* dt_proj_b  = (const float*)d_in[6];
    const float* A_log      = (const float*)d_in[7];
    const float* Dp         = (const float*)d_in[8];
    const float* out_proj_w = (const float*)d_in[9];
    float* out = (float*)d_out;

    const size_t M = 1024 * 1024;
    float* ws_f = (float*)d_ws;
    float* xz   = ws_f;                          // 8M floats (b,l,1024)   [K1 -> K2]
    float* xq   = ws_f + 8 * M;                  // 4M (b,l,512)           [K2 -> scans]
    float* xdbl = ws_f + 12 * M;                 // 0.5M (b,64,l)          [K3 -> scans]
    unsigned short* ycb = (unsigned short*)(ws_f + 12 * M + 512 * 1024);  // 8M bf16 (b,l,1024)
    unsigned short* Hb  = (unsigned short*)(ws_f + 16 * M + 512 * 1024);  // 4M bf16
    unsigned short* Wb  = (unsigned short*)(ws_f + 18 * M + 512 * 1024);  // 0.5M bf16
    unsigned short* Wob = (unsigned short*)(ws_f + 18 * M + 768 * 1024);  // 0.5M bf16
    // aliases onto xz (dead after conv):  B*NC*DSTATE*DHALF = 4M floats each
    float* pend = xz;                            // 4M
    float* hend = xz + 4 * M;                    // 4M (becomes carry-in after scan2)

    dim3 blk(256);

    cast_bf16_k<<<dim3((BB * LL * DMODEL / 4 + 255) / 256), blk, 0, stream>>>(hidden, Hb, BB * LL * DMODEL / 4);
    cast_bf16_k<<<dim3((DINNER * DMODEL / 4 + 255) / 256), blk, 0, stream>>>(in_proj_w, Wb, DINNER * DMODEL / 4);
    cast_bf16_k<<<dim3((DMODEL * DINNER / 4 + 255) / 256), blk, 0, stream>>>(out_proj_w, Wob, DMODEL * DINNER / 4);

    // K1: in_proj (bf16 MFMA) -> xz (b,l,1024) fp32
    gemm_mfma<DMODEL, DINNER><<<dim3(BB * LL / 128, DINNER / 128), blk, 0, stream>>>(Wb, Hb, xz);
    // K2: conv + silu -> xq fp32 (b,l,512); z-half -> ycb bf16 cols 512..1023
    conv_silu<<<dim3(LL / 64, DINNER / 64, BB), blk, 0, stream>>>(xz, conv_x_w, conv_z_w, xq, ycb);
    // K3: x_proj (fp32) -> xdbl (b,64,l)
    gemm_we_xl<NCH, DHALF><<<dim3(LL / 64, 1, BB), blk, 0, stream>>>(x_proj_w, xq, xdbl);
    // K5: fused dt + chunk-local scan   [xz dead -> pend/hend alias]
    scan1<<<dim3(NC, DHALF / 256, BB), blk, 0, stream>>>(xq, xdbl, A_log, dt_proj_w, dt_proj_b, pend, hend);
    // K5b: cross-chunk combine (in-place carry into hend)
    scan2<<<dim3(BB * DSTATE * DHALF / 256), blk, 0, stream>>>(pend, hend);
    // K6: fused dt + recompute with carry -> ycb bf16 cols 0..511
    scan3<<<dim3(NC, DHALF / 256, BB), blk, 0, stream>>>(xq, xdbl, A_log, dt_proj_w, dt_proj_b, Dp, hend, ycb);
    // K7: out_proj (bf16 MFMA) -> out (b,l,512) fp32
    gemm_mfma<DINNER, DMODEL><<<dim3(BB * LL / 128, DMODEL / 128), blk, 0, stream>>>(Wob, ycb, out);
}

// Round 4
// 148.875 us; speedup vs baseline: 2.8755x; 1.1694x over previous
//
#include <hip/hip_runtime.h>
#include <math.h>

#define BB 2
#define LL 4096
#define DMODEL 512
#define DINNER 1024
#define DHALF 512
#define DSTATE 16
#define RK 32
#define NCH 64          // x_dbl channels (32 dt + 16 B + 16 C)
#define NC 256          // scan chunks
#define CLEN (LL/NC)    // 16
#define NG 16           // chunk groups (for scan2)
#define GL (NC/NG)      // 16 chunks per group

typedef __attribute__((ext_vector_type(8))) short short8;
typedef __attribute__((ext_vector_type(4))) float f32x4;

__device__ __forceinline__ float silu_f(float v) { return v / (1.f + __expf(-v)); }

// round-to-nearest-even fp32 -> bf16 (inputs finite)
__device__ __forceinline__ unsigned short f2bf(float x) {
    unsigned int u = __float_as_uint(x);
    u += 0x7fffu + ((u >> 16) & 1u);
    return (unsigned short)(u >> 16);
}
__device__ __forceinline__ float bf2f(unsigned short u) {
    return __uint_as_float((unsigned int)u << 16);
}

__device__ __forceinline__ float softplus_f(float x) {
    return fmaxf(x, 0.f) + __logf(1.f + __expf(-fabsf(x)));
}

__device__ __forceinline__ void gload16(const unsigned short* g, unsigned short* l) {
    __builtin_amdgcn_global_load_lds((const __attribute__((address_space(1))) void*)g,
                                     (__attribute__((address_space(3))) void*)l, 16, 0, 0);
}

// ---------------- one cast kernel for all fp32->bf16 conversions ----------------
#define H4  1048576   // hidden vec4 count
#define W14 131072    // in_proj
#define W24 131072    // out_proj
#define W34 8192      // x_proj
__global__ void cast_all(const float* __restrict__ hid, const float* __restrict__ w1,
                         const float* __restrict__ w2, const float* __restrict__ w3,
                         unsigned short* __restrict__ Hb, unsigned short* __restrict__ Wb,
                         unsigned short* __restrict__ Wob, unsigned short* __restrict__ Wxb) {
    int i = blockIdx.x * 256 + threadIdx.x;
    const float* src; unsigned short* dst; int j;
    if (i < H4)                    { src = hid; dst = Hb;  j = i; }
    else if (i < H4 + W14)         { src = w1;  dst = Wb;  j = i - H4; }
    else if (i < H4 + W14 + W24)   { src = w2;  dst = Wob; j = i - H4 - W14; }
    else if (i < H4 + W14 + W24 + W34) { src = w3; dst = Wxb; j = i - H4 - W14 - W24; }
    else return;
    float4 v = *(const float4*)&src[(size_t)j * 4];
    ushort4 o = make_ushort4(f2bf(v.x), f2bf(v.y), f2bf(v.z), f2bf(v.w));
    *(ushort4*)&dst[(size_t)j * 4] = o;
}

// ---------------- bf16 MFMA GEMM, 128x128 tile ----------------
// W: [E][K] bf16 k-major.  X: [R][K] bf16 k-major.  out[r][e] = sum_k W[e][k]*X[r][k]
// BF16OUT: write bf16 (ushort) else fp32.
template<int K, int E, bool BF16OUT>
__global__ __launch_bounds__(256) void gemm_mfma(const unsigned short* __restrict__ W,
                                                 const unsigned short* __restrict__ X,
                                                 void* __restrict__ outv) {
    __shared__ unsigned short Wa[128 * 64];   // [row][k], 16B-chunk XOR-swizzled
    __shared__ unsigned short Xa[128 * 64];
    const int tid = threadIdx.x;
    const int lane = tid & 63;
    const int w = tid >> 6;
    const int wr = w >> 1, wc = w & 1;
    const int frow = lane & 15;
    const int kg = lane >> 4;
    const int e0 = blockIdx.y * 128;
    const int r0 = blockIdx.x * 128;

    f32x4 acc[4][4] = {};

    for (int kt = 0; kt < K / 64; ++kt) {
        #pragma unroll
        for (int i = 0; i < 4; ++i) {
            int flat = i * 256 + tid;         // 16B units
            int row = flat >> 3;
            int slot = flat & 7;
            int chunk = slot ^ (row & 7);
            gload16(&W[(size_t)(e0 + row) * K + kt * 64 + chunk * 8], &Wa[flat * 8]);
            gload16(&X[(size_t)(r0 + row) * K + kt * 64 + chunk * 8], &Xa[flat * 8]);
        }
        __syncthreads();

        #pragma unroll
        for (int ks = 0; ks < 2; ++ks) {
            short8 af[4], bfr[4];
            #pragma unroll
            for (int m = 0; m < 4; ++m) {
                int row = wr * 64 + m * 16 + frow;
                int phys = (ks * 4 + kg) ^ (row & 7);
                af[m] = *(const short8*)&Wa[row * 64 + phys * 8];
            }
            #pragma unroll
            for (int n = 0; n < 4; ++n) {
                int row = wc * 64 + n * 16 + frow;
                int phys = (ks * 4 + kg) ^ (row & 7);
                bfr[n] = *(const short8*)&Xa[row * 64 + phys * 8];
            }
            #pragma unroll
            for (int m = 0; m < 4; ++m)
                #pragma unroll
                for (int n = 0; n < 4; ++n)
                    acc[m][n] = __builtin_amdgcn_mfma_f32_16x16x32_bf16(af[m], bfr[n], acc[m][n], 0, 0, 0);
        }
        __syncthreads();
    }

    #pragma unroll
    for (int m = 0; m < 4; ++m) {
        #pragma unroll
        for (int n = 0; n < 4; ++n) {
            int e = e0 + wr * 64 + m * 16 + kg * 4;
            int r = r0 + wc * 64 + n * 16 + frow;
            f32x4 a = acc[m][n];
            if constexpr (BF16OUT) {
                ushort4 o = make_ushort4(f2bf(a.x), f2bf(a.y), f2bf(a.z), f2bf(a.w));
                *(ushort4*)&((unsigned short*)outv)[(size_t)r * E + e] = o;
            } else {
                *(f32x4*)&((float*)outv)[(size_t)r * E + e] = a;
            }
        }
    }
}

// ---------------- x_proj MFMA: 128r x 64e tile, out (b, ch, l) fp32 ----------------
// X: [8192][512] bf16, W: [64][512] bf16, out: xdbl (b,64,l)
__global__ __launch_bounds__(256) void gemm_xproj(const unsigned short* __restrict__ W,
                                                  const unsigned short* __restrict__ X,
                                                  float* __restrict__ out) {
    __shared__ unsigned short Xa[128 * 64];
    __shared__ unsigned short Wa[64 * 64];
    const int tid = threadIdx.x;
    const int lane = tid & 63;
    const int w = tid >> 6;
    const int frow = lane & 15;
    const int kg = lane >> 4;
    const int r0 = blockIdx.x * 128;

    f32x4 acc[4][2] = {};

    for (int kt = 0; kt < 512 / 64; ++kt) {
        #pragma unroll
        for (int i = 0; i < 4; ++i) {
            int flat = i * 256 + tid;
            int row = flat >> 3;
            int slot = flat & 7;
            int chunk = slot ^ (row & 7);
            gload16(&X[(size_t)(r0 + row) * 512 + kt * 64 + chunk * 8], &Xa[flat * 8]);
        }
        #pragma unroll
        for (int i = 0; i < 2; ++i) {
            int flat = i * 256 + tid;         // 0..511
            int row = flat >> 3;              // 0..63
            int slot = flat & 7;
            int chunk = slot ^ (row & 7);
            gload16(&W[(size_t)row * 512 + kt * 64 + chunk * 8], &Wa[flat * 8]);
        }
        __syncthreads();

        #pragma unroll
        for (int ks = 0; ks < 2; ++ks) {
            short8 af[4], bfr[2];
            #pragma unroll
            for (int m = 0; m < 4; ++m) {
                int row = m * 16 + frow;
                int phys = (ks * 4 + kg) ^ (row & 7);
                af[m] = *(const short8*)&Wa[row * 64 + phys * 8];
            }
            #pragma unroll
            for (int n = 0; n < 2; ++n) {
                int row = w * 32 + n * 16 + frow;
                int phys = (ks * 4 + kg) ^ (row & 7);
                bfr[n] = *(const short8*)&Xa[row * 64 + phys * 8];
            }
            #pragma unroll
            for (int m = 0; m < 4; ++m)
                #pragma unroll
                for (int n = 0; n < 2; ++n)
                    acc[m][n] = __builtin_amdgcn_mfma_f32_16x16x32_bf16(af[m], bfr[n], acc[m][n], 0, 0, 0);
        }
        __syncthreads();
    }

    #pragma unroll
    for (int m = 0; m < 4; ++m) {
        #pragma unroll
        for (int n = 0; n < 2; ++n) {
            int r = r0 + w * 32 + n * 16 + frow;
            int b = r >> 12;
            int l = r & (LL - 1);
            int e = m * 16 + kg * 4;
            #pragma unroll
            for (int i = 0; i < 4; ++i)
                out[((size_t)b * NCH + e + i) * LL + l] = acc[m][n][i];
        }
    }
}

// ---------------- conv1d (width 4, taps l-1..l+2) + silu, bf16 input ----------------
// xzb: (b, l, 1024) bf16.  x-half -> xq fp32 + xqb bf16 (b,l,512); z-half -> ycb cols 512..1023
__global__ void conv_silu(const unsigned short* __restrict__ xzb,
                          const float* __restrict__ wx, const float* __restrict__ wz,
                          float* __restrict__ xq, unsigned short* __restrict__ xqb,
                          unsigned short* __restrict__ ycb) {
    __shared__ float s[67][64];
    const int b = blockIdx.z;
    const int l0 = blockIdx.x * 64;
    const int c0 = blockIdx.y * 64;
    const int tid = threadIdx.x;
    for (int idx = tid; idx < 67 * 16; idx += 256) {
        int rr = idx >> 4, u = idx & 15;
        int l = l0 - 1 + rr;
        float4 f;
        if (l >= 0 && l < LL) {
            ushort4 v = *(const ushort4*)&xzb[((size_t)b * LL + l) * DINNER + c0 + u * 4];
            f = make_float4(bf2f(v.x), bf2f(v.y), bf2f(v.z), bf2f(v.w));
        } else f = make_float4(0.f, 0.f, 0.f, 0.f);
        *(float4*)&s[rr][u * 4] = f;
    }
    __syncthreads();
    const int cc = tid & 63;
    const int c = c0 + cc;
    const bool isx = (c < DHALF);
    const float* wp = isx ? &wx[c * 4] : &wz[(c - DHALF) * 4];
    float4 w = *(const float4*)wp;
    #pragma unroll
    for (int rep = 0; rep < 16; ++rep) {
        int ll = (tid >> 6) + rep * 4;
        float v = w.x * s[ll][cc] + w.y * s[ll + 1][cc] + w.z * s[ll + 2][cc] + w.w * s[ll + 3][cc];
        v = silu_f(v);
        int l = l0 + ll;
        if (isx) {
            xq[((size_t)b * LL + l) * DHALF + c] = v;
            xqb[((size_t)b * LL + l) * DHALF + c] = f2bf(v);
        } else {
            ycb[((size_t)b * LL + l) * DINNER + c] = f2bf(v);
        }
    }
}

// ---------------- scan pass 1: fused dt + chunk-local scan -> (prodA, h_end) ----------------
// xdbl (b, 64, l): ch 0..31 = dt_rank rows, 32..47 = B, 48..63 = C
__global__ __launch_bounds__(256) void scan1(const float* __restrict__ xq,
                      const float* __restrict__ xdbl, const float* __restrict__ A_log,
                      const float* __restrict__ dtw, const float* __restrict__ dtb,
                      float* __restrict__ pend, float* __restrict__ hend) {
    __shared__ float s[48][CLEN];
    const int b = blockIdx.z;
    const int d = blockIdx.y * 256 + threadIdx.x;
    const int c = blockIdx.x;
    const int tid = threadIdx.x;
    for (int idx = tid; idx < 48 * CLEN; idx += 256) {
        int ch = idx >> 4, ll = idx & (CLEN - 1);
        s[ch][ll] = xdbl[((size_t)b * NCH + ch) * LL + c * CLEN + ll];
    }
    float dtwreg[RK];
    #pragma unroll
    for (int r = 0; r < RK; r += 4) {
        float4 v = *(const float4*)&dtw[d * RK + r];
        dtwreg[r] = v.x; dtwreg[r+1] = v.y; dtwreg[r+2] = v.z; dtwreg[r+3] = v.w;
    }
    float Arow[DSTATE];
    #pragma unroll
    for (int n = 0; n < DSTATE; ++n) Arow[n] = -expf(A_log[d * DSTATE + n]);
    const float bias = dtb[d];
    float del[CLEN];
    #pragma unroll
    for (int t = 0; t < CLEN; ++t) del[t] = bias;
    __syncthreads();
    #pragma unroll
    for (int r = 0; r < RK; ++r) {
        float wv = dtwreg[r];
        #pragma unroll
        for (int q = 0; q < CLEN / 4; ++q) {
            float4 v = *(const float4*)&s[r][q * 4];
            del[q*4+0] = fmaf(v.x, wv, del[q*4+0]);
            del[q*4+1] = fmaf(v.y, wv, del[q*4+1]);
            del[q*4+2] = fmaf(v.z, wv, del[q*4+2]);
            del[q*4+3] = fmaf(v.w, wv, del[q*4+3]);
        }
    }
    #pragma unroll
    for (int t = 0; t < CLEN; ++t) del[t] = softplus_f(del[t]);

    float h[DSTATE], p[DSTATE];
    #pragma unroll
    for (int n = 0; n < DSTATE; ++n) { h[n] = 0.f; p[n] = 1.f; }
    #pragma unroll
    for (int t = 0; t < CLEN; ++t) {
        float dl = del[t];
        float xv = xq[((size_t)b * LL + c * CLEN + t) * DHALF + d];
        float dx = dl * xv;
        #pragma unroll
        for (int n = 0; n < DSTATE; ++n) {
            float dA = __expf(dl * Arow[n]);
            h[n] = fmaf(dA, h[n], dx * s[32 + n][t]);
            p[n] *= dA;
        }
    }
    size_t base = (((size_t)b * NC + c) * DSTATE) * DHALF + d;
    #pragma unroll
    for (int n = 0; n < DSTATE; ++n) {
        pend[base + (size_t)n * DHALF] = p[n];
        hend[base + (size_t)n * DHALF] = h[n];
    }
}

// ---------------- scan2a: within-group prefix (in place) + group totals ----------------
__global__ void scan2a(float* __restrict__ pend, float* __restrict__ hend,
                       float* __restrict__ gP, float* __restrict__ gH) {
    int flat = blockIdx.x * 256 + threadIdx.x;   // B*NG*DSTATE*DHALF = 262144
    int d = flat & (DHALF - 1);
    int n = (flat >> 9) & (DSTATE - 1);
    int g = (flat >> 13) & (NG - 1);
    int b = flat >> 17;
    const size_t stride = (size_t)DSTATE * DHALF;
    size_t idx = (((size_t)b * NC + g * GL) * DSTATE + n) * DHALF + d;
    float P = 1.f, H = 0.f;
    #pragma unroll 4
    for (int j = 0; j < GL; ++j) {
        float p = pend[idx], h = hend[idx];
        pend[idx] = P; hend[idx] = H;
        H = fmaf(p, H, h);
        P *= p;
        idx += stride;
    }
    size_t gi = (((size_t)b * NG + g) * DSTATE + n) * DHALF + d;
    gP[gi] = P; gH[gi] = H;
}

// ---------------- scan2b: serial group-carry scan (gH becomes carry-IN) ----------------
__global__ void scan2b(const float* __restrict__ gP, float* __restrict__ gH) {
    int flat = blockIdx.x * 256 + threadIdx.x;   // B*DSTATE*DHALF = 16384
    int d = flat & (DHALF - 1);
    int n = (flat >> 9) & (DSTATE - 1);
    int b = flat >> 13;
    float h = 0.f;
    const size_t stride = (size_t)DSTATE * DHALF;
    size_t gi = (((size_t)b * NG) * DSTATE + n) * DHALF + d;
    for (int g = 0; g < NG; ++g) {
        float P = gP[gi], Hh = gH[gi];
        gH[gi] = h;
        h = fmaf(P, h, Hh);
        gi += stride;
    }
}

// ---------------- scan pass 3: fused dt + recompute with carry -> ycb bf16 cols 0..511 ----
__global__ __launch_bounds__(256) void scan3(const float* __restrict__ xq,
                      const float* __restrict__ xdbl, const float* __restrict__ A_log,
                      const float* __restrict__ dtw, const float* __restrict__ dtb,
                      const float* __restrict__ Dp, const float* __restrict__ pend,
                      const float* __restrict__ hend, const float* __restrict__ gH,
                      unsigned short* __restrict__ ycb) {
    __shared__ float s[64][CLEN];
    const int b = blockIdx.z;
    const int d = blockIdx.y * 256 + threadIdx.x;
    const int c = blockIdx.x;
    const int tid = threadIdx.x;
    for (int idx = tid; idx < 64 * CLEN; idx += 256) {
        int ch = idx >> 4, ll = idx & (CLEN - 1);
        s[ch][ll] = xdbl[((size_t)b * NCH + ch) * LL + c * CLEN + ll];
    }
    float dtwreg[RK];
    #pragma unroll
    for (int r = 0; r < RK; r += 4) {
        float4 v = *(const float4*)&dtw[d * RK + r];
        dtwreg[r] = v.x; dtwreg[r+1] = v.y; dtwreg[r+2] = v.z; dtwreg[r+3] = v.w;
    }
    float Arow[DSTATE], h[DSTATE];
    size_t base = (((size_t)b * NC + c) * DSTATE) * DHALF + d;
    size_t gbase = (((size_t)b * NG + (c >> 4)) * DSTATE) * DHALF + d;
    #pragma unroll
    for (int n = 0; n < DSTATE; ++n) {
        Arow[n] = -expf(A_log[d * DSTATE + n]);
        h[n] = fmaf(pend[base + (size_t)n * DHALF], gH[gbase + (size_t)n * DHALF],
                    hend[base + (size_t)n * DHALF]);
    }
    const float bias = dtb[d];
    const float Dv = Dp[d];
    float del[CLEN];
    #pragma unroll
    for (int t = 0; t < CLEN; ++t) del[t] = bias;
    __syncthreads();
    #pragma unroll
    for (int r = 0; r < RK; ++r) {
        float wv = dtwreg[r];
        #pragma unroll
        for (int q = 0; q < CLEN / 4; ++q) {
            float4 v = *(const float4*)&s[r][q * 4];
            del[q*4+0] = fmaf(v.x, wv, del[q*4+0]);
            del[q*4+1] = fmaf(v.y, wv, del[q*4+1]);
            del[q*4+2] = fmaf(v.z, wv, del[q*4+2]);
            del[q*4+3] = fmaf(v.w, wv, del[q*4+3]);
        }
    }
    #pragma unroll
    for (int t = 0; t < CLEN; ++t) del[t] = softplus_f(del[t]);

    #pragma unroll
    for (int t = 0; t < CLEN; ++t) {
        float dl = del[t];
        float xv = xq[((size_t)b * LL + c * CLEN + t) * DHALF + d];
        float dx = dl * xv;
        float y = Dv * xv;
        #pragma unroll
        for (int n = 0; n < DSTATE; ++n) {
            float dA = __expf(dl * Arow[n]);
            h[n] = fmaf(dA, h[n], dx * s[32 + n][t]);
            y = fmaf(h[n], s[48 + n][t], y);
        }
        ycb[((size_t)b * LL + c * CLEN + t) * DINNER + d] = f2bf(y);
    }
}

extern "C" void kernel_launch(void* const* d_in, const int* in_sizes, int n_in,
                              void* d_out, int out_size, void* d_ws, size_t ws_size,
                              hipStream_t stream) {
    const float* hidden     = (const float*)d_in[0];
    const float* in_proj_w  = (const float*)d_in[1];
    const float* conv_x_w   = (const float*)d_in[2];
    const float* conv_z_w   = (const float*)d_in[3];
    const float* x_proj_w   = (const float*)d_in[4];
    const float* dt_proj_w  = (const float*)d_in[5];
    const float* dt_proj_b  = (const float*)d_in[6];
    const float* A_log      = (const float*)d_in[7];
    const float* Dp         = (const float*)d_in[8];
    const float* out_proj_w = (const float*)d_in[9];
    float* out = (float*)d_out;

    float* ws_f = (float*)d_ws;
    // float offsets (1 float = 2 bf16)
    unsigned short* Wb  = (unsigned short*)(ws_f + 0);         // 512K bf16 (1 MB)
    unsigned short* Wob = (unsigned short*)(ws_f + 262144);    // 512K bf16
    unsigned short* Wxb = (unsigned short*)(ws_f + 524288);    // 32K bf16
    unsigned short* xzb = (unsigned short*)(ws_f + 540672);    // 8M bf16 (b,l,1024) [K1->conv; then pend]
    float* xq   = ws_f + 4734976;                              // 4M f32 (b,l,512)
    unsigned short* xqb = (unsigned short*)(ws_f + 8929280);   // 4M bf16 [conv->K3; then hend lo]
    unsigned short* Hb  = (unsigned short*)(ws_f + 11026432);  // 4M bf16 [cast->K1; then hend hi]
    unsigned short* ycb = (unsigned short*)(ws_f + 13123584);  // 8M bf16 (b,l,1024)
    float* xdbl = ws_f + 17317888;                             // 512K f32 (b,64,l)
    float* gP   = ws_f + 17842176;                             // 256K f32
    float* gH   = ws_f + 18104320;                             // 256K f32  (end: 73.5 MB)
    // aliases (dead regions at scan time):
    float* pend = (float*)xzb;                                 // 4M f32
    float* hend = (float*)xqb;                                 // 4M f32 (spans xqb+Hb)

    dim3 blk(256);

    // K0: all casts in one kernel
    cast_all<<<dim3((H4 + W14 + W24 + W34 + 255) / 256), blk, 0, stream>>>(
        hidden, in_proj_w, out_proj_w, x_proj_w, Hb, Wb, Wob, Wxb);
    // K1: in_proj (bf16 MFMA) -> xzb bf16 (b,l,1024)
    gemm_mfma<DMODEL, DINNER, true><<<dim3(BB * LL / 128, DINNER / 128), blk, 0, stream>>>(Wb, Hb, xzb);
    // K2: conv + silu -> xq fp32 + xqb bf16; z-half -> ycb cols 512..1023
    conv_silu<<<dim3(LL / 64, DINNER / 64, BB), blk, 0, stream>>>(xzb, conv_x_w, conv_z_w, xq, xqb, ycb);
    // K3: x_proj (bf16 MFMA) -> xdbl (b,64,l) fp32
    gemm_xproj<<<dim3(BB * LL / 128), blk, 0, stream>>>(Wxb, xqb, xdbl);
    // K5: fused dt + chunk-local scan  [xzb/xqb/Hb dead -> pend/hend]
    scan1<<<dim3(NC, DHALF / 256, BB), blk, 0, stream>>>(xq, xdbl, A_log, dt_proj_w, dt_proj_b, pend, hend);
    // K5b/c: two-level cross-chunk combine
    scan2a<<<dim3(BB * NG * DSTATE * DHALF / 256), blk, 0, stream>>>(pend, hend, gP, gH);
    scan2b<<<dim3(BB * DSTATE * DHALF / 256), blk, 0, stream>>>(gP, gH);
    // K6: fused dt + recompute with carry -> ycb bf16 cols 0..511
    scan3<<<dim3(NC, DHALF / 256, BB), blk, 0, stream>>>(xq, xdbl, A_log, dt_proj_w, dt_proj_b,
                                                         Dp, pend, hend, gH, ycb);
    // K7: out_proj (bf16 MFMA) -> out (b,l,512) fp32
    gemm_mfma<DINNER, DMODEL, false><<<dim3(BB * LL / 128, DMODEL / 128), blk, 0, stream>>>(Wob, ycb, out);
}

// Round 5
// 134.762 us; speedup vs baseline: 3.1766x; 1.1047x over previous
//
#include <hip/hip_runtime.h>
#include <math.h>

#define BB 2
#define LL 4096
#define DMODEL 512
#define DINNER 1024
#define DHALF 512
#define DSTATE 16
#define RK 32
#define NCH 64          // x_dbl channels (32 dt + 16 B + 16 C)
#define NC 128          // scan chunks
#define CLEN (LL/NC)    // 32
#define NG 16           // chunk groups (for scan2)
#define GL (NC/NG)      // 8 chunks per group

typedef __attribute__((ext_vector_type(8))) short short8;
typedef __attribute__((ext_vector_type(4))) float f32x4;

__device__ __forceinline__ float silu_f(float v) { return v / (1.f + __expf(-v)); }

// round-to-nearest-even fp32 -> bf16 (inputs finite)
__device__ __forceinline__ unsigned short f2bf(float x) {
    unsigned int u = __float_as_uint(x);
    u += 0x7fffu + ((u >> 16) & 1u);
    return (unsigned short)(u >> 16);
}
__device__ __forceinline__ float bf2f(unsigned short u) {
    return __uint_as_float((unsigned int)u << 16);
}

__device__ __forceinline__ float softplus_f(float x) {
    return fmaxf(x, 0.f) + __logf(1.f + __expf(-fabsf(x)));
}

__device__ __forceinline__ void gload16(const unsigned short* g, unsigned short* l) {
    __builtin_amdgcn_global_load_lds((const __attribute__((address_space(1))) void*)g,
                                     (__attribute__((address_space(3))) void*)l, 16, 0, 0);
}

// ---------------- one cast kernel for all fp32->bf16 conversions ----------------
#define H4  1048576   // hidden vec4 count
#define W14 131072    // in_proj
#define W24 131072    // out_proj
#define W34 8192      // x_proj
__global__ void cast_all(const float* __restrict__ hid, const float* __restrict__ w1,
                         const float* __restrict__ w2, const float* __restrict__ w3,
                         unsigned short* __restrict__ Hb, unsigned short* __restrict__ Wb,
                         unsigned short* __restrict__ Wob, unsigned short* __restrict__ Wxb) {
    int i = blockIdx.x * 256 + threadIdx.x;
    const float* src; unsigned short* dst; int j;
    if (i < H4)                    { src = hid; dst = Hb;  j = i; }
    else if (i < H4 + W14)         { src = w1;  dst = Wb;  j = i - H4; }
    else if (i < H4 + W14 + W24)   { src = w2;  dst = Wob; j = i - H4 - W14; }
    else if (i < H4 + W14 + W24 + W34) { src = w3; dst = Wxb; j = i - H4 - W14 - W24; }
    else return;
    float4 v = *(const float4*)&src[(size_t)j * 4];
    ushort4 o = make_ushort4(f2bf(v.x), f2bf(v.y), f2bf(v.z), f2bf(v.w));
    *(ushort4*)&dst[(size_t)j * 4] = o;
}

// ---------------- bf16 MFMA GEMM, 128x128 tile ----------------
// W: [E][K] bf16 k-major.  X: [R][K] bf16 k-major.  out[r][e] = sum_k W[e][k]*X[r][k]
template<int K, int E, bool BF16OUT>
__global__ __launch_bounds__(256) void gemm_mfma(const unsigned short* __restrict__ W,
                                                 const unsigned short* __restrict__ X,
                                                 void* __restrict__ outv) {
    __shared__ unsigned short Wa[128 * 64];   // [row][k], 16B-chunk XOR-swizzled
    __shared__ unsigned short Xa[128 * 64];
    const int tid = threadIdx.x;
    const int lane = tid & 63;
    const int w = tid >> 6;
    const int wr = w >> 1, wc = w & 1;
    const int frow = lane & 15;
    const int kg = lane >> 4;
    const int e0 = blockIdx.y * 128;
    const int r0 = blockIdx.x * 128;

    f32x4 acc[4][4] = {};

    for (int kt = 0; kt < K / 64; ++kt) {
        #pragma unroll
        for (int i = 0; i < 4; ++i) {
            int flat = i * 256 + tid;         // 16B units
            int row = flat >> 3;
            int slot = flat & 7;
            int chunk = slot ^ (row & 7);
            gload16(&W[(size_t)(e0 + row) * K + kt * 64 + chunk * 8], &Wa[flat * 8]);
            gload16(&X[(size_t)(r0 + row) * K + kt * 64 + chunk * 8], &Xa[flat * 8]);
        }
        __syncthreads();

        #pragma unroll
        for (int ks = 0; ks < 2; ++ks) {
            short8 af[4], bfr[4];
            #pragma unroll
            for (int m = 0; m < 4; ++m) {
                int row = wr * 64 + m * 16 + frow;
                int phys = (ks * 4 + kg) ^ (row & 7);
                af[m] = *(const short8*)&Wa[row * 64 + phys * 8];
            }
            #pragma unroll
            for (int n = 0; n < 4; ++n) {
                int row = wc * 64 + n * 16 + frow;
                int phys = (ks * 4 + kg) ^ (row & 7);
                bfr[n] = *(const short8*)&Xa[row * 64 + phys * 8];
            }
            #pragma unroll
            for (int m = 0; m < 4; ++m)
                #pragma unroll
                for (int n = 0; n < 4; ++n)
                    acc[m][n] = __builtin_amdgcn_mfma_f32_16x16x32_bf16(af[m], bfr[n], acc[m][n], 0, 0, 0);
        }
        __syncthreads();
    }

    #pragma unroll
    for (int m = 0; m < 4; ++m) {
        #pragma unroll
        for (int n = 0; n < 4; ++n) {
            int e = e0 + wr * 64 + m * 16 + kg * 4;
            int r = r0 + wc * 64 + n * 16 + frow;
            f32x4 a = acc[m][n];
            if constexpr (BF16OUT) {
                ushort4 o = make_ushort4(f2bf(a.x), f2bf(a.y), f2bf(a.z), f2bf(a.w));
                *(ushort4*)&((unsigned short*)outv)[(size_t)r * E + e] = o;
            } else {
                *(f32x4*)&((float*)outv)[(size_t)r * E + e] = a;
            }
        }
    }
}

// ---------------- x_proj MFMA: 128r x 64e tile, out (b, ch, l) fp32 ----------------
__global__ __launch_bounds__(256) void gemm_xproj(const unsigned short* __restrict__ W,
                                                  const unsigned short* __restrict__ X,
                                                  float* __restrict__ out) {
    __shared__ unsigned short Xa[128 * 64];
    __shared__ unsigned short Wa[64 * 64];
    const int tid = threadIdx.x;
    const int lane = tid & 63;
    const int w = tid >> 6;
    const int frow = lane & 15;
    const int kg = lane >> 4;
    const int r0 = blockIdx.x * 128;

    f32x4 acc[4][2] = {};

    for (int kt = 0; kt < 512 / 64; ++kt) {
        #pragma unroll
        for (int i = 0; i < 4; ++i) {
            int flat = i * 256 + tid;
            int row = flat >> 3;
            int slot = flat & 7;
            int chunk = slot ^ (row & 7);
            gload16(&X[(size_t)(r0 + row) * 512 + kt * 64 + chunk * 8], &Xa[flat * 8]);
        }
        #pragma unroll
        for (int i = 0; i < 2; ++i) {
            int flat = i * 256 + tid;
            int row = flat >> 3;
            int slot = flat & 7;
            int chunk = slot ^ (row & 7);
            gload16(&W[(size_t)row * 512 + kt * 64 + chunk * 8], &Wa[flat * 8]);
        }
        __syncthreads();

        #pragma unroll
        for (int ks = 0; ks < 2; ++ks) {
            short8 af[4], bfr[2];
            #pragma unroll
            for (int m = 0; m < 4; ++m) {
                int row = m * 16 + frow;
                int phys = (ks * 4 + kg) ^ (row & 7);
                af[m] = *(const short8*)&Wa[row * 64 + phys * 8];
            }
            #pragma unroll
            for (int n = 0; n < 2; ++n) {
                int row = w * 32 + n * 16 + frow;
                int phys = (ks * 4 + kg) ^ (row & 7);
                bfr[n] = *(const short8*)&Xa[row * 64 + phys * 8];
            }
            #pragma unroll
            for (int m = 0; m < 4; ++m)
                #pragma unroll
                for (int n = 0; n < 2; ++n)
                    acc[m][n] = __builtin_amdgcn_mfma_f32_16x16x32_bf16(af[m], bfr[n], acc[m][n], 0, 0, 0);
        }
        __syncthreads();
    }

    #pragma unroll
    for (int m = 0; m < 4; ++m) {
        #pragma unroll
        for (int n = 0; n < 2; ++n) {
            int r = r0 + w * 32 + n * 16 + frow;
            int b = r >> 12;
            int l = r & (LL - 1);
            int e = m * 16 + kg * 4;
            #pragma unroll
            for (int i = 0; i < 4; ++i)
                out[((size_t)b * NCH + e + i) * LL + l] = acc[m][n][i];
        }
    }
}

// ---------------- conv1d (width 4, taps l-1..l+2) + silu, bf16 in/out ----------------
// xzb: (b,l,1024) bf16. x-half -> xqb bf16 (b,l,512); z-half -> ycb cols 512..1023
// Each thread owns 4 consecutive channels -> ushort4 stores.
__global__ void conv_silu(const unsigned short* __restrict__ xzb,
                          const float* __restrict__ wx, const float* __restrict__ wz,
                          unsigned short* __restrict__ xqb, unsigned short* __restrict__ ycb) {
    __shared__ float s[67][64];
    const int b = blockIdx.z;
    const int l0 = blockIdx.x * 64;
    const int c0 = blockIdx.y * 64;
    const int tid = threadIdx.x;
    for (int idx = tid; idx < 67 * 16; idx += 256) {
        int rr = idx >> 4, u = idx & 15;
        int l = l0 - 1 + rr;
        float4 f;
        if (l >= 0 && l < LL) {
            ushort4 v = *(const ushort4*)&xzb[((size_t)b * LL + l) * DINNER + c0 + u * 4];
            f = make_float4(bf2f(v.x), bf2f(v.y), bf2f(v.z), bf2f(v.w));
        } else f = make_float4(0.f, 0.f, 0.f, 0.f);
        *(float4*)&s[rr][u * 4] = f;
    }
    __syncthreads();
    const int ct = (tid & 15) * 4;       // 4 consecutive channels
    const int c = c0 + ct;
    const bool isx = (c < DHALF);
    const float* wp = isx ? &wx[c * 4] : &wz[(c - DHALF) * 4];
    float4 w0 = *(const float4*)&wp[0];
    float4 w1 = *(const float4*)&wp[4];
    float4 w2 = *(const float4*)&wp[8];
    float4 w3 = *(const float4*)&wp[12];
    #pragma unroll
    for (int rep = 0; rep < 4; ++rep) {
        int ll = (tid >> 4) + rep * 16;
        float4 t0 = *(const float4*)&s[ll][ct];
        float4 t1 = *(const float4*)&s[ll + 1][ct];
        float4 t2 = *(const float4*)&s[ll + 2][ct];
        float4 t3 = *(const float4*)&s[ll + 3][ct];
        float v0 = w0.x*t0.x + w0.y*t1.x + w0.z*t2.x + w0.w*t3.x;
        float v1 = w1.x*t0.y + w1.y*t1.y + w1.z*t2.y + w1.w*t3.y;
        float v2 = w2.x*t0.z + w2.y*t1.z + w2.z*t2.z + w2.w*t3.z;
        float v3 = w3.x*t0.w + w3.y*t1.w + w3.z*t2.w + w3.w*t3.w;
        ushort4 o = make_ushort4(f2bf(silu_f(v0)), f2bf(silu_f(v1)),
                                 f2bf(silu_f(v2)), f2bf(silu_f(v3)));
        int l = l0 + ll;
        if (isx) *(ushort4*)&xqb[((size_t)b * LL + l) * DHALF + c] = o;
        else     *(ushort4*)&ycb[((size_t)b * LL + l) * DINNER + c] = o;
    }
}

// ---------------- scan pass 1: fused dt + chunk-local scan -> (prodA, h_end) ----------------
// xdbl (b, 64, l): ch 0..31 = dt_rank rows, 32..47 = B, 48..63 = C
__global__ __launch_bounds__(256) void scan1(const unsigned short* __restrict__ xqb,
                      const float* __restrict__ xdbl, const float* __restrict__ A_log,
                      const float* __restrict__ dtw, const float* __restrict__ dtb,
                      float* __restrict__ pend, float* __restrict__ hend) {
    __shared__ float s[48][CLEN];
    const int b = blockIdx.z;
    const int d = blockIdx.y * 256 + threadIdx.x;
    const int c = blockIdx.x;
    const int tid = threadIdx.x;
    for (int idx = tid; idx < 48 * CLEN; idx += 256) {
        int ch = idx / CLEN, ll = idx % CLEN;
        s[ch][ll] = xdbl[((size_t)b * NCH + ch) * LL + c * CLEN + ll];
    }
    float dtwreg[RK];
    #pragma unroll
    for (int r = 0; r < RK; r += 4) {
        float4 v = *(const float4*)&dtw[d * RK + r];
        dtwreg[r] = v.x; dtwreg[r+1] = v.y; dtwreg[r+2] = v.z; dtwreg[r+3] = v.w;
    }
    float Arow[DSTATE];
    #pragma unroll
    for (int n = 0; n < DSTATE; ++n) Arow[n] = -expf(A_log[d * DSTATE + n]);
    const float bias = dtb[d];
    float del[CLEN];
    #pragma unroll
    for (int t = 0; t < CLEN; ++t) del[t] = bias;
    __syncthreads();
    #pragma unroll
    for (int r = 0; r < RK; ++r) {
        float wv = dtwreg[r];
        #pragma unroll
        for (int q = 0; q < CLEN / 4; ++q) {
            float4 v = *(const float4*)&s[r][q * 4];
            del[q*4+0] = fmaf(v.x, wv, del[q*4+0]);
            del[q*4+1] = fmaf(v.y, wv, del[q*4+1]);
            del[q*4+2] = fmaf(v.z, wv, del[q*4+2]);
            del[q*4+3] = fmaf(v.w, wv, del[q*4+3]);
        }
    }
    #pragma unroll
    for (int t = 0; t < CLEN; ++t) del[t] = softplus_f(del[t]);

    float h[DSTATE], p[DSTATE];
    #pragma unroll
    for (int n = 0; n < DSTATE; ++n) { h[n] = 0.f; p[n] = 1.f; }
    #pragma unroll
    for (int t = 0; t < CLEN; ++t) {
        float dl = del[t];
        float xv = bf2f(xqb[((size_t)b * LL + c * CLEN + t) * DHALF + d]);
        float dx = dl * xv;
        #pragma unroll
        for (int n = 0; n < DSTATE; ++n) {
            float dA = __expf(dl * Arow[n]);
            h[n] = fmaf(dA, h[n], dx * s[32 + n][t]);
            p[n] *= dA;
        }
    }
    size_t base = (((size_t)b * NC + c) * DSTATE) * DHALF + d;
    #pragma unroll
    for (int n = 0; n < DSTATE; ++n) {
        pend[base + (size_t)n * DHALF] = p[n];
        hend[base + (size_t)n * DHALF] = h[n];
    }
}

// ---------------- scan2a: within-group prefix (in place) + group totals ----------------
__global__ void scan2a(float* __restrict__ pend, float* __restrict__ hend,
                       float* __restrict__ gP, float* __restrict__ gH) {
    int flat = blockIdx.x * 256 + threadIdx.x;   // B*NG*DSTATE*DHALF = 262144
    int d = flat & (DHALF - 1);
    int n = (flat >> 9) & (DSTATE - 1);
    int g = (flat >> 13) & (NG - 1);
    int b = flat >> 17;
    const size_t stride = (size_t)DSTATE * DHALF;
    size_t idx = (((size_t)b * NC + g * GL) * DSTATE + n) * DHALF + d;
    float P = 1.f, H = 0.f;
    #pragma unroll
    for (int j = 0; j < GL; ++j) {
        float p = pend[idx], h = hend[idx];
        pend[idx] = P; hend[idx] = H;
        H = fmaf(p, H, h);
        P *= p;
        idx += stride;
    }
    size_t gi = (((size_t)b * NG + g) * DSTATE + n) * DHALF + d;
    gP[gi] = P; gH[gi] = H;
}

// ---------------- scan2b: serial group-carry scan (gH becomes carry-IN) ----------------
__global__ void scan2b(const float* __restrict__ gP, float* __restrict__ gH) {
    int flat = blockIdx.x * 256 + threadIdx.x;   // B*DSTATE*DHALF = 16384
    int d = flat & (DHALF - 1);
    int n = (flat >> 9) & (DSTATE - 1);
    int b = flat >> 13;
    float h = 0.f;
    const size_t stride = (size_t)DSTATE * DHALF;
    size_t gi = (((size_t)b * NG) * DSTATE + n) * DHALF + d;
    for (int g = 0; g < NG; ++g) {
        float P = gP[gi], Hh = gH[gi];
        gH[gi] = h;
        h = fmaf(P, h, Hh);
        gi += stride;
    }
}

// ---------------- scan pass 3: fused dt + recompute with carry -> ycb bf16 cols 0..511 ----
__global__ __launch_bounds__(256) void scan3(const unsigned short* __restrict__ xqb,
                      const float* __restrict__ xdbl, const float* __restrict__ A_log,
                      const float* __restrict__ dtw, const float* __restrict__ dtb,
                      const float* __restrict__ Dp, const float* __restrict__ pend,
                      const float* __restrict__ hend, const float* __restrict__ gH,
                      unsigned short* __restrict__ ycb) {
    __shared__ float s[64][CLEN];
    const int b = blockIdx.z;
    const int d = blockIdx.y * 256 + threadIdx.x;
    const int c = blockIdx.x;
    const int tid = threadIdx.x;
    for (int idx = tid; idx < 64 * CLEN; idx += 256) {
        int ch = idx / CLEN, ll = idx % CLEN;
        s[ch][ll] = xdbl[((size_t)b * NCH + ch) * LL + c * CLEN + ll];
    }
    float dtwreg[RK];
    #pragma unroll
    for (int r = 0; r < RK; r += 4) {
        float4 v = *(const float4*)&dtw[d * RK + r];
        dtwreg[r] = v.x; dtwreg[r+1] = v.y; dtwreg[r+2] = v.z; dtwreg[r+3] = v.w;
    }
    float Arow[DSTATE], h[DSTATE];
    size_t base = (((size_t)b * NC + c) * DSTATE) * DHALF + d;
    size_t gbase = (((size_t)b * NG + (c / GL)) * DSTATE) * DHALF + d;
    #pragma unroll
    for (int n = 0; n < DSTATE; ++n) {
        Arow[n] = -expf(A_log[d * DSTATE + n]);
        h[n] = fmaf(pend[base + (size_t)n * DHALF], gH[gbase + (size_t)n * DHALF],
                    hend[base + (size_t)n * DHALF]);
    }
    const float bias = dtb[d];
    const float Dv = Dp[d];
    float del[CLEN];
    #pragma unroll
    for (int t = 0; t < CLEN; ++t) del[t] = bias;
    __syncthreads();
    #pragma unroll
    for (int r = 0; r < RK; ++r) {
        float wv = dtwreg[r];
        #pragma unroll
        for (int q = 0; q < CLEN / 4; ++q) {
            float4 v = *(const float4*)&s[r][q * 4];
            del[q*4+0] = fmaf(v.x, wv, del[q*4+0]);
            del[q*4+1] = fmaf(v.y, wv, del[q*4+1]);
            del[q*4+2] = fmaf(v.z, wv, del[q*4+2]);
            del[q*4+3] = fmaf(v.w, wv, del[q*4+3]);
        }
    }
    #pragma unroll
    for (int t = 0; t < CLEN; ++t) del[t] = softplus_f(del[t]);

    #pragma unroll
    for (int t = 0; t < CLEN; ++t) {
        float dl = del[t];
        float xv = bf2f(xqb[((size_t)b * LL + c * CLEN + t) * DHALF + d]);
        float dx = dl * xv;
        float y = Dv * xv;
        #pragma unroll
        for (int n = 0; n < DSTATE; ++n) {
            float dA = __expf(dl * Arow[n]);
            h[n] = fmaf(dA, h[n], dx * s[32 + n][t]);
            y = fmaf(h[n], s[48 + n][t], y);
        }
        ycb[((size_t)b * LL + c * CLEN + t) * DINNER + d] = f2bf(y);
    }
}

extern "C" void kernel_launch(void* const* d_in, const int* in_sizes, int n_in,
                              void* d_out, int out_size, void* d_ws, size_t ws_size,
                              hipStream_t stream) {
    const float* hidden     = (const float*)d_in[0];
    const float* in_proj_w  = (const float*)d_in[1];
    const float* conv_x_w   = (const float*)d_in[2];
    const float* conv_z_w   = (const float*)d_in[3];
    const float* x_proj_w   = (const float*)d_in[4];
    const float* dt_proj_w  = (const float*)d_in[5];
    const float* dt_proj_b  = (const float*)d_in[6];
    const float* A_log      = (const float*)d_in[7];
    const float* Dp         = (const float*)d_in[8];
    const float* out_proj_w = (const float*)d_in[9];
    float* out = (float*)d_out;

    float* ws_f = (float*)d_ws;
    // float-unit offsets
    unsigned short* Wb  = (unsigned short*)(ws_f + 0);         // 1 MB
    unsigned short* Wob = (unsigned short*)(ws_f + 262144);    // 1 MB
    unsigned short* Wxb = (unsigned short*)(ws_f + 524288);    // 64 KB
    unsigned short* Hb  = (unsigned short*)(ws_f + 540672);    // 8 MB bf16 [cast->K1; then hend]
    unsigned short* xzb = (unsigned short*)(ws_f + 2637824);   // 16 MB bf16 [K1->conv; then pend]
    unsigned short* xqb = (unsigned short*)(ws_f + 6832128);   // 8 MB bf16 (b,l,512)
    unsigned short* ycb = (unsigned short*)(ws_f + 8929280);   // 16 MB bf16 (b,l,1024)
    float* xdbl = ws_f + 13123584;                             // 2 MB f32 (b,64,l)
    float* gP   = ws_f + 13647872;                             // 1 MB
    float* gH   = ws_f + 13910016;                             // 1 MB   (end ~56.7 MB)
    // aliases (dead at scan time):
    float* pend = ws_f + 2637824;                              // 8 MB (over xzb)
    float* hend = ws_f + 540672;                               // 8 MB (over Hb)

    dim3 blk(256);

    // K0: all casts in one kernel
    cast_all<<<dim3((H4 + W14 + W24 + W34 + 255) / 256), blk, 0, stream>>>(
        hidden, in_proj_w, out_proj_w, x_proj_w, Hb, Wb, Wob, Wxb);
    // K1: in_proj (bf16 MFMA) -> xzb bf16 (b,l,1024)
    gemm_mfma<DMODEL, DINNER, true><<<dim3(BB * LL / 128, DINNER / 128), blk, 0, stream>>>(Wb, Hb, xzb);
    // K2: conv + silu -> xqb bf16; z-half -> ycb cols 512..1023
    conv_silu<<<dim3(LL / 64, DINNER / 64, BB), blk, 0, stream>>>(xzb, conv_x_w, conv_z_w, xqb, ycb);
    // K3: x_proj (bf16 MFMA) -> xdbl (b,64,l) fp32
    gemm_xproj<<<dim3(BB * LL / 128), blk, 0, stream>>>(Wxb, xqb, xdbl);
    // K5: fused dt + chunk-local scan  [xzb/Hb dead -> pend/hend]
    scan1<<<dim3(NC, DHALF / 256, BB), blk, 0, stream>>>(xqb, xdbl, A_log, dt_proj_w, dt_proj_b, pend, hend);
    // K5b/c: two-level cross-chunk combine
    scan2a<<<dim3(BB * NG * DSTATE * DHALF / 256), blk, 0, stream>>>(pend, hend, gP, gH);
    scan2b<<<dim3(BB * DSTATE * DHALF / 256), blk, 0, stream>>>(gP, gH);
    // K6: fused dt + recompute with carry -> ycb bf16 cols 0..511
    scan3<<<dim3(NC, DHALF / 256, BB), blk, 0, stream>>>(xqb, xdbl, A_log, dt_proj_w, dt_proj_b,
                                                         Dp, pend, hend, gH, ycb);
    // K7: out_proj (bf16 MFMA) -> out (b,l,512) fp32
    gemm_mfma<DINNER, DMODEL, false><<<dim3(BB * LL / 128, DMODEL / 128), blk, 0, stream>>>(Wob, ycb, out);
}